// Round 2
// baseline (8683.899 us; speedup 1.0000x reference)
//
#include <hip/hip_runtime.h>

// HetSTGCNBlock fp32 baseline, round 2: fixed workspace offsets.
// t1 needs 16*400*1920 = 12,288,000 floats (was wrongly 1,228,800 -> buffer
// overlap corrupted batches b>=1). tk aliases u1B (+S4 headroom) to save 49 MB.
// Workspace requirement: ~188 MB (47,006,112 floats).

#define BB 16
#define NNODES 400
#define NA 81
#define NB 319
#define T1 30
#define T2 28
#define CC 64
#define M1 (T1*CC)   // 1920
#define ITILE 32

__device__ __forceinline__ float sigmoidf_(float x) { return 1.0f / (1.0f + __expf(-x)); }

// ---------------- prep: transposes + weight reshapes ----------------
__global__ void k_prep_all(
    const float* __restrict__ A00, const float* __restrict__ A01,
    const float* __restrict__ A10, const float* __restrict__ A11,
    const float* __restrict__ g1t1, const float* __restrict__ g1t2, const float* __restrict__ g1t3,
    const float* __restrict__ g2t1, const float* __restrict__ g2t2, const float* __restrict__ g2t3,
    const float* __restrict__ theta,
    const float* __restrict__ w11, const float* __restrict__ b11,
    const float* __restrict__ wc1, const float* __restrict__ bc1,
    const float* __restrict__ w12, const float* __restrict__ b12,
    const float* __restrict__ wc2, const float* __restrict__ bc2,
    float* __restrict__ A00t, float* __restrict__ A11t,
    float* __restrict__ A01t, float* __restrict__ A10t,
    float* __restrict__ thT, float* __restrict__ thetaT,
    float* __restrict__ W1t, float* __restrict__ B1t, float* __restrict__ B2t,
    float* __restrict__ W2t) {
  int idx = blockIdx.x * blockDim.x + threadIdx.x;
  if (idx < 7776) {                 // A00t [j=81][i pad 96]
    int j = idx / 96, i = idx % 96;
    A00t[idx] = (i < 81) ? A00[i * 81 + j] : 0.f;
    return;
  }
  idx -= 7776;
  if (idx < 102080) {               // A11t [j=319][i pad 320]
    int j = idx / 320, i = idx % 320;
    A11t[idx] = (i < 319) ? A11[i * 319 + j] : 0.f;
    return;
  }
  idx -= 102080;
  if (idx < 30624) {                // A01t [j=319][i pad 96]  (A01 is 81x319)
    int j = idx / 96, i = idx % 96;
    A01t[idx] = (i < 81) ? A01[i * 319 + j] : 0.f;
    return;
  }
  idx -= 30624;
  if (idx < 25920) {                // A10t [j=81][i pad 320]  (A10 is 319x81)
    int j = idx / 320, i = idx % 320;
    A10t[idx] = (i < 319) ? A10[i * 81 + j] : 0.f;
    return;
  }
  idx -= 25920;
  if (idx < 122880) {               // theta tensors transposed: [tt][l][co][ci] = src[l][ci][co]
    int tt = idx / 20480, rem = idx % 20480;
    int l = rem / 4096, e = rem % 4096;
    int co = e >> 6, ci = e & 63;
    const float* src = tt == 0 ? g1t1 : tt == 1 ? g1t2 : tt == 2 ? g1t3
                     : tt == 3 ? g2t1 : tt == 4 ? g2t2 : g2t3;
    thT[idx] = src[l * 4096 + ci * 64 + co];
    return;
  }
  idx -= 122880;
  if (idx < 4096) { int co = idx >> 6, ci = idx & 63; thetaT[idx] = theta[ci * 64 + co]; return; }
  idx -= 4096;
  if (idx < 1152) {                 // W1t [kk=6][cc=192]
    int kk = idx / 192, cc = idx % 192;
    int k = kk >> 1, ci = kk & 1;
    W1t[idx] = (cc < 64) ? w11[cc * 6 + ci * 3 + k] : wc1[(cc - 64) * 6 + ci * 3 + k];
    return;
  }
  idx -= 1152;
  if (idx < 192) { B1t[idx] = (idx < 64) ? b11[idx] : bc1[idx - 64]; return; }
  idx -= 192;
  if (idx < 192) { B2t[idx] = (idx < 64) ? b12[idx] : bc2[idx - 64]; return; }
  idx -= 192;
  if (idx < 36864) {                // W2t [kk=192][cc=192]
    int kk = idx / 192, cc = idx % 192;
    int k = kk >> 6, ci = kk & 63;
    W2t[idx] = (cc < 64) ? w12[cc * 192 + ci * 3 + k] : wc2[(cc - 64) * 192 + ci * 3 + k];
    return;
  }
}

// Mat = (A01@A10)^T padded [j=81][i pad 96]; Mbt = (A10@A01)^T [j=319][i pad 320]
__global__ void k_prep_mm(const float* __restrict__ A01, const float* __restrict__ A10,
                          float* __restrict__ Mat, float* __restrict__ Mbt) {
  int idx = blockIdx.x * blockDim.x + threadIdx.x;
  if (idx < 7776) {
    int j = idx / 96, i = idx % 96;
    float acc = 0.f;
    if (i < 81)
      for (int k = 0; k < 319; ++k) acc += A01[i * 319 + k] * A10[k * 81 + j];
    Mat[idx] = acc;
  } else {
    idx -= 7776;
    if (idx >= 102080) return;
    int j = idx / 320, i = idx % 320;
    float acc = 0.f;
    if (i < 319)
      for (int k = 0; k < 81; ++k) acc += A10[i * 81 + k] * A01[k * 319 + j];
    Mbt[idx] = acc;
  }
}

// ---------------- temporal conv 1 (Cin=2), gated ----------------
__global__ __launch_bounds__(192) void k_tconv1(const float* __restrict__ X,
                                                const float* __restrict__ W1t,
                                                const float* __restrict__ B1t,
                                                float* __restrict__ t1) {
  __shared__ float xl[64];
  __shared__ float wl[6 * 192];
  __shared__ float bl[192];
  __shared__ float ol[T1 * 192];
  int bn = blockIdx.x;
  int tid = threadIdx.x;
  if (tid < 64) xl[tid] = X[(size_t)bn * 64 + tid];
  for (int i2 = tid; i2 < 6 * 192; i2 += 192) wl[i2] = W1t[i2];
  bl[tid] = B1t[tid];
  __syncthreads();
  int cc = tid;
  float acc[T1];
  float bias = bl[cc];
#pragma unroll
  for (int t = 0; t < T1; ++t) acc[t] = bias;
#pragma unroll
  for (int kk = 0; kk < 6; ++kk) {
    float w = wl[kk * 192 + cc];
    int k = kk >> 1, ci = kk & 1;
#pragma unroll
    for (int t = 0; t < T1; ++t) acc[t] += xl[(t + k) * 2 + ci] * w;
  }
#pragma unroll
  for (int t = 0; t < T1; ++t) ol[t * 192 + cc] = acc[t];
  __syncthreads();
  for (int p = tid; p < T1 * 64; p += 192) {
    int t = p >> 6, c = p & 63;
    float v = (ol[t * 192 + 64 + c] + ol[t * 192 + c]) * sigmoidf_(ol[t * 192 + 128 + c]);
    t1[(size_t)bn * M1 + p] = v;
  }
}

// ---------------- node gemm: Out[b,i,m] = sum_j At[j][i] * Xin[b,j,m] ----------------
__global__ __launch_bounds__(192) void k_gemm_node(const float* __restrict__ At, int I, int J,
                                                   int Ipad,
                                                   const float* __restrict__ Xin, int xbs,
                                                   float* __restrict__ Out, int obs) {
  int tid = threadIdx.x;
  int m0 = blockIdx.x * 192;
  int i0 = blockIdx.y * ITILE;
  int b = blockIdx.z;
  float acc[ITILE];
#pragma unroll
  for (int q = 0; q < ITILE; ++q) acc[q] = 0.f;
  const float* xp = Xin + (size_t)b * xbs + m0 + tid;
  for (int j = 0; j < J; ++j) {
    float x = xp[(size_t)j * M1];
    const float* ar = At + (size_t)j * Ipad + i0;
#pragma unroll
    for (int q4 = 0; q4 < ITILE / 4; ++q4) {
      float4 a = *(const float4*)(ar + q4 * 4);
      acc[q4 * 4 + 0] += a.x * x;
      acc[q4 * 4 + 1] += a.y * x;
      acc[q4 * 4 + 2] += a.z * x;
      acc[q4 * 4 + 3] += a.w * x;
    }
  }
  float* op = Out + (size_t)b * obs + m0 + tid;
#pragma unroll
  for (int q = 0; q < ITILE; ++q)
    if (i0 + q < I) op[(size_t)(i0 + q) * M1] = acc[q];
}

// ---------------- fused het conv: dual node-gemm + channel matmuls + activations ----------------
__global__ __launch_bounds__(192) void k_fused_het(
    const float* __restrict__ A1t, const float* __restrict__ A2t, int I, int Ipad,
    const float* __restrict__ Us, int ubs,
    const float* __restrict__ S4, int s4bs,
    const float* __restrict__ X00, int xbs,
    const float* __restrict__ th1T, const float* __restrict__ th2T,
    const float* __restrict__ th3T,
    float* __restrict__ Out, int obs) {
  __shared__ float s1l[ITILE * 192];
  __shared__ float s3l[ITILE * 192];
  int tid = threadIdx.x;
  int m0 = blockIdx.x * 192;
  int i0 = blockIdx.y * ITILE;
  int b = blockIdx.z;
  float acc1[ITILE], acc3[ITILE];
#pragma unroll
  for (int q = 0; q < ITILE; ++q) { acc1[q] = 0.f; acc3[q] = 0.f; }
  const float* up = Us + (size_t)b * ubs + m0 + tid;
  for (int j = 0; j < I; ++j) {
    float x = up[(size_t)j * M1];
    const float* ar1 = A1t + (size_t)j * Ipad + i0;
    const float* ar2 = A2t + (size_t)j * Ipad + i0;
#pragma unroll
    for (int q4 = 0; q4 < ITILE / 4; ++q4) {
      float4 a = *(const float4*)(ar1 + q4 * 4);
      float4 c4 = *(const float4*)(ar2 + q4 * 4);
      acc1[q4 * 4 + 0] += a.x * x;
      acc1[q4 * 4 + 1] += a.y * x;
      acc1[q4 * 4 + 2] += a.z * x;
      acc1[q4 * 4 + 3] += a.w * x;
      acc3[q4 * 4 + 0] += c4.x * x;
      acc3[q4 * 4 + 1] += c4.y * x;
      acc3[q4 * 4 + 2] += c4.z * x;
      acc3[q4 * 4 + 3] += c4.w * x;
    }
  }
#pragma unroll
  for (int q = 0; q < ITILE; ++q) {
    s1l[q * 192 + tid] = acc1[q];
    s3l[q * 192 + tid] = acc3[q];
  }
  __syncthreads();
  int c = tid & 63;
  int tl = tid >> 6;  // 0..2
  const float4* w1p = (const float4*)(th1T + c * 64);
  const float4* w2p = (const float4*)(th2T + c * 64);
  const float4* w3p = (const float4*)(th3T + c * 64);
  for (int q = 0; q < ITILE; ++q) {
    int i = i0 + q;
    if (i >= I) break;
    const float4* s1r = (const float4*)(s1l + q * 192 + tl * 64);
    const float4* s3r = (const float4*)(s3l + q * 192 + tl * 64);
    const float4* s4r = (const float4*)(S4 + (size_t)b * s4bs + (size_t)i * M1 + m0 + tl * 64);
    float u2 = 0.f, pp = 0.f, qq = 0.f;
#pragma unroll
    for (int k4 = 0; k4 < 16; ++k4) {
      float4 sv = s1r[k4], wv = w1p[k4];
      u2 += sv.x * wv.x + sv.y * wv.y + sv.z * wv.z + sv.w * wv.w;
      float4 s3v = s3r[k4], w2v = w2p[k4];
      pp += s3v.x * w2v.x + s3v.y * w2v.y + s3v.z * w2v.z + s3v.w * w2v.w;
      float4 s4v = s4r[k4], w3v = w3p[k4];
      qq += s4v.x * w3v.x + s4v.y * w3v.y + s4v.z * w3v.z + s4v.w * w3v.w;
    }
    float u2r = fmaxf(u2, 0.f);
    float u5 = sigmoidf_(pp + qq);
    float u6 = fmaxf(0.5f * (u2r + u5), 0.f);
    float x0 = X00[(size_t)b * xbs + (size_t)i * M1 + m0 + tl * 64 + c];
    Out[(size_t)b * obs + (size_t)i * M1 + m0 + tl * 64 + c] =
        fmaxf(0.9f * u6 + 0.1f * x0, 0.f);
  }
}

// ---------------- theta channel matmul + relu ----------------
__global__ __launch_bounds__(256) void k_theta(const float* __restrict__ u0f,
                                               const float* __restrict__ u1f,
                                               const float* __restrict__ thT,
                                               float* __restrict__ tk) {
  int tid = threadIdx.x;
  int c = tid & 63, g = tid >> 6;
  const float4* wr = (const float4*)(thT + c * 64);
  for (int it = 0; it < 24; ++it) {
    int quad = blockIdx.x * 24 + it;
    int R = quad * 4 + g;
    int brow = R / 12000;
    int rem = R % 12000;
    int n = rem / 30;
    int t = rem % 30;
    const float* src = (n < NA)
        ? (u0f + (((size_t)brow * NA + n) * 30 + t) * 64)
        : (u1f + (((size_t)brow * NB + (n - NA)) * 30 + t) * 64);
    float xin[64];
    const float4* sp = (const float4*)src;
#pragma unroll
    for (int k4 = 0; k4 < 16; ++k4) {
      float4 v = sp[k4];
      xin[k4 * 4] = v.x; xin[k4 * 4 + 1] = v.y; xin[k4 * 4 + 2] = v.z; xin[k4 * 4 + 3] = v.w;
    }
    float acc = 0.f;
#pragma unroll
    for (int k4 = 0; k4 < 16; ++k4) {
      float4 wv = wr[k4];
      acc += xin[k4 * 4] * wv.x + xin[k4 * 4 + 1] * wv.y + xin[k4 * 4 + 2] * wv.z +
             xin[k4 * 4 + 3] * wv.w;
    }
    tk[(size_t)R * 64 + c] = fmaxf(acc, 0.f);
  }
}

// ---------------- temporal conv 2 (Cin=64), gated, writes d_out ----------------
__global__ __launch_bounds__(192) void k_tconv2(const float* __restrict__ tk,
                                                const float* __restrict__ W2t,
                                                const float* __restrict__ B2t,
                                                float* __restrict__ out) {
  __shared__ float inlT[64 * 36];   // [ci][t] padded
  __shared__ float ol[T2 * 192];
  int bn = blockIdx.x, tid = threadIdx.x;
  for (int p = tid; p < 1920; p += 192) {
    int t = p >> 6, c = p & 63;
    inlT[c * 36 + t] = tk[(size_t)bn * M1 + p];
  }
  __syncthreads();
  int cc = tid;
  float acc[T2];
  float bias = B2t[cc];
#pragma unroll
  for (int t = 0; t < T2; ++t) acc[t] = bias;
  for (int ci = 0; ci < 64; ++ci) {
    float x[32];
    const float4* xp = (const float4*)(inlT + ci * 36);
#pragma unroll
    for (int q = 0; q < 8; ++q) {
      float4 v = xp[q];
      x[q * 4] = v.x; x[q * 4 + 1] = v.y; x[q * 4 + 2] = v.z; x[q * 4 + 3] = v.w;
    }
#pragma unroll
    for (int k = 0; k < 3; ++k) {
      float w = W2t[(k * 64 + ci) * 192 + cc];
#pragma unroll
      for (int t = 0; t < T2; ++t) acc[t] += x[t + k] * w;
    }
  }
#pragma unroll
  for (int t = 0; t < T2; ++t) ol[t * 192 + cc] = acc[t];
  __syncthreads();
  for (int p = tid; p < T2 * 64; p += 192) {
    int t = p >> 6, c = p & 63;
    float v = (ol[t * 192 + 64 + c] + ol[t * 192 + c]) * sigmoidf_(ol[t * 192 + 128 + c]);
    out[(size_t)bn * (T2 * 64) + p] = v;
  }
}

// ---------------- batchnorm over (b,t,c) per node ----------------
__global__ __launch_bounds__(256) void k_bn_stats(const float* __restrict__ y,
                                                  float* __restrict__ stats) {
  int n = blockIdx.x;
  int tid = threadIdx.x;
  float s = 0.f, ss = 0.f;
  for (int b = 0; b < BB; ++b) {
    const float* p = y + ((size_t)(b * NNODES + n)) * (T2 * 64);
    for (int i2 = tid; i2 < T2 * 64; i2 += 256) {
      float v = p[i2];
      s += v;
      ss += v * v;
    }
  }
  __shared__ float rs[4], rss[4];
  for (int off = 32; off > 0; off >>= 1) {
    s += __shfl_down(s, off);
    ss += __shfl_down(ss, off);
  }
  if ((tid & 63) == 0) { rs[tid >> 6] = s; rss[tid >> 6] = ss; }
  __syncthreads();
  if (tid == 0) {
    float S = rs[0] + rs[1] + rs[2] + rs[3];
    float SS = rss[0] + rss[1] + rss[2] + rss[3];
    float mean = S / 28672.f;
    float var = SS / 28672.f - mean * mean;
    stats[n] = mean;
    stats[NNODES + n] = rsqrtf(var + 1e-5f);
  }
}

__global__ void k_bn_apply(float* __restrict__ y, const float* __restrict__ stats,
                           const float* __restrict__ gamma, const float* __restrict__ beta) {
  int idx = blockIdx.x * blockDim.x + threadIdx.x;
  const int total = BB * NNODES * T2 * 64 / 4;
  for (; idx < total; idx += gridDim.x * blockDim.x) {
    int e = idx * 4;
    int n = (e / (T2 * 64)) % NNODES;
    float mean = stats[n];
    float g = gamma[n] * stats[NNODES + n];
    float bt = beta[n];
    float4 v = ((float4*)y)[idx];
    v.x = (v.x - mean) * g + bt;
    v.y = (v.y - mean) * g + bt;
    v.z = (v.z - mean) * g + bt;
    v.w = (v.w - mean) * g + bt;
    ((float4*)y)[idx] = v;
  }
}

// ---------------- host launcher ----------------
extern "C" void kernel_launch(void* const* d_in, const int* in_sizes, int n_in,
                              void* d_out, int out_size, void* d_ws, size_t ws_size,
                              hipStream_t stream) {
  const float* X     = (const float*)d_in[0];
  const float* A00   = (const float*)d_in[1];
  const float* A01   = (const float*)d_in[2];
  const float* A10   = (const float*)d_in[3];
  const float* A11   = (const float*)d_in[4];
  const float* w11   = (const float*)d_in[5];
  const float* b11   = (const float*)d_in[6];
  const float* wc1   = (const float*)d_in[7];
  const float* bc1   = (const float*)d_in[8];
  const float* g1t1  = (const float*)d_in[9];
  const float* g1t2  = (const float*)d_in[10];
  const float* g1t3  = (const float*)d_in[11];
  const float* g2t1  = (const float*)d_in[12];
  const float* g2t2  = (const float*)d_in[13];
  const float* g2t3  = (const float*)d_in[14];
  const float* theta = (const float*)d_in[15];
  const float* w12   = (const float*)d_in[16];
  const float* b12   = (const float*)d_in[17];
  const float* wc2   = (const float*)d_in[18];
  const float* bc2   = (const float*)d_in[19];
  const float* gamma = (const float*)d_in[20];
  const float* beta  = (const float*)d_in[21];

  // workspace layout (floats). t1 = 16*400*30*64 = 12,288,000.
  float* w = (float*)d_ws;
  float* t1     = w;                    // 12,288,000
  float* u0A    = t1 + 12288000;        // 2,488,320
  float* u0B    = u0A + 2488320;        // 2,488,320
  float* u1A    = u0B + 2488320;        // 9,799,680
  float* u1B    = u1A + 9799680;        // 9,799,680
  float* S4     = u1B + 9799680;        // 9,799,680
  float* A00t   = S4 + 9799680;         // 7,776
  float* A11t   = A00t + 7776;          // 102,080
  float* A01t   = A11t + 102080;        // 30,624
  float* A10t   = A01t + 30624;         // 25,920
  float* thT    = A10t + 25920;         // 122,880
  float* thetaT = thT + 122880;         // 4,096
  float* W1t    = thetaT + 4096;        // 1,152
  float* B1t    = W1t + 1152;           // 192
  float* B2t    = B1t + 192;            // 192
  float* W2t    = B2t + 192;            // 36,864
  float* Mat    = W2t + 36864;          // 7,776
  float* Mbt    = Mat + 7776;           // 102,080
  float* stats  = Mbt + 102080;         // 800
  // tk (12,288,000) aliases u1B..S4 (19,599,360 available) — k_theta reads
  // only u0A/u1A (the final layer-5 buffers), so no overlap hazard.
  float* tk     = u1B;

  k_prep_all<<<1296, 256, 0, stream>>>(A00, A01, A10, A11, g1t1, g1t2, g1t3, g2t1, g2t2,
                                       g2t3, theta, w11, b11, wc1, bc1, w12, b12, wc2, bc2,
                                       A00t, A11t, A01t, A10t, thT, thetaT, W1t, B1t, B2t,
                                       W2t);
  k_prep_mm<<<430, 256, 0, stream>>>(A01, A10, Mat, Mbt);
  k_tconv1<<<BB * NNODES, 192, 0, stream>>>(X, W1t, B1t, t1);

  float* cu0 = t1;            int cu0bs = NNODES * M1;  // rows 0..80 of t1
  float* cu1 = t1 + NA * M1;  int cu1bs = NNODES * M1;  // rows 81..399
  const int u0bs = NA * M1;   // 155,520
  const int u1bs = NB * M1;   // 612,480

  for (int l = 0; l < 5; ++l) {
    // S4a = A01 @ cu1  (81 rows)
    k_gemm_node<<<dim3(10, 3, BB), 192, 0, stream>>>(A01t, NA, NB, 96, cu1, cu1bs, S4, u0bs);
    float* nu0 = (l & 1) ? u0B : u0A;
    k_fused_het<<<dim3(10, 3, BB), 192, 0, stream>>>(
        A00t, Mat, NA, 96, cu0, cu0bs, S4, u0bs, t1, NNODES * M1,
        thT + 0 * 20480 + l * 4096, thT + 1 * 20480 + l * 4096, thT + 2 * 20480 + l * 4096,
        nu0, u0bs);
    // S4b = A10 @ nu0  (319 rows)
    k_gemm_node<<<dim3(10, 10, BB), 192, 0, stream>>>(A10t, NB, NA, 320, nu0, u0bs, S4, u1bs);
    float* nu1 = (l & 1) ? u1B : u1A;
    k_fused_het<<<dim3(10, 10, BB), 192, 0, stream>>>(
        A11t, Mbt, NB, 320, cu1, cu1bs, S4, u1bs, t1 + NA * M1, NNODES * M1,
        thT + 3 * 20480 + l * 4096, thT + 4 * 20480 + l * 4096, thT + 5 * 20480 + l * 4096,
        nu1, u1bs);
    cu0 = nu0; cu0bs = u0bs;
    cu1 = nu1; cu1bs = u1bs;
  }
  // final: cu0 = u0A, cu1 = u1A (5 layers, last l=4 writes the A buffers)

  // tk = relu(concat(u0,u1) @ theta)  -> tk buffer (aliases u1B/S4, safe)
  k_theta<<<2000, 256, 0, stream>>>(cu0, cu1, thetaT, tk);
  // temporal conv 2 + gating -> d_out
  k_tconv2<<<BB * NNODES, 192, 0, stream>>>(tk, W2t, B2t, (float*)d_out);
  // batchnorm per node, in place on d_out
  k_bn_stats<<<NNODES, 256, 0, stream>>>((float*)d_out, stats);
  k_bn_apply<<<2048, 256, 0, stream>>>((float*)d_out, stats, gamma, beta);
}

// Round 3
// 1549.738 us; speedup vs baseline: 5.6035x; 5.6035x over previous
//
#include <hip/hip_runtime.h>

// HetSTGCNBlock round 3: bf16 MFMA pipeline (mfma_f32_16x16x32_bf16, fp32 accum).
// Activations bf16 m-major [b][m=t*64+c][node_pad]; S buffers node-major [b][i][m].
// All static operands pre-packed into MFMA B-fragment order on device.
// Frag layouts (HW-verified per guide): A: row=lane&15, k=(lane>>4)*8+e;
// B: col=lane&15, k=(lane>>4)*8+e; D: col=lane&15, row=(lane>>4)*4+reg.

typedef __attribute__((ext_vector_type(8))) short short8v;
typedef __attribute__((ext_vector_type(4))) float f32x4;

#define BB 16
#define NA 81
#define NB 319
#define PA 128
#define PB 320
#define M1 1920     // 30*64
#define T1 30
#define T2 28
#define TKLD 2176   // tk row pad (conv2 t-pad rows overread up to 31*64+191=2175)

#define MFMA16 __builtin_amdgcn_mfma_f32_16x16x32_bf16

__device__ __forceinline__ float sigmoidf_(float x){ return 1.0f/(1.0f+__expf(-x)); }
__device__ __forceinline__ short f2bf(float f){
  unsigned u = __float_as_uint(f);
  u += 0x7FFF + ((u>>16)&1);
  return (short)(u>>16);
}
__device__ __forceinline__ float bf2f(short s){
  return __uint_as_float(((unsigned)(unsigned short)s)<<16);
}

// ---------- prep: Ma = A01@A10 (81x81), Mb = A10@A01 (319x319), fp32 ----------
__global__ __launch_bounds__(256) void k_prep_mm(const float* __restrict__ A01,
                                                 const float* __restrict__ A10,
                                                 float* __restrict__ Ma,
                                                 float* __restrict__ Mb) {
  int idx = blockIdx.x*256 + threadIdx.x;
  if (idx < NA*NA) {
    int i = idx / NA, j = idx % NA;
    float a = 0.f;
    for (int k = 0; k < NB; ++k) a += A01[i*NB + k]*A10[k*NA + j];
    Ma[idx] = a;
  } else {
    idx -= NA*NA;
    if (idx >= NB*NB) return;
    int i = idx / NB, j = idx % NB;
    float a = 0.f;
    for (int k = 0; k < NA; ++k) a += A10[i*NA + k]*A01[k*NB + j];
    Mb[idx] = a;
  }
}

// ---------- pack mixing matrices into B-frag order, bf16 ----------
// Bpk flat = ((jt*nIt + it)*64 + lane)*8 + e ; value = A[i][j], i=it*16+(l&15),
// j=jt*32+(l>>4)*8+e, zero-padded.
__device__ __forceinline__ void packA_one(int f, const float* src, int I, int J,
                                          int ld, int nIt, short* dst) {
  int e = f & 7, l = (f >> 3) & 63, rest = f >> 9;
  int it = rest % nIt, jt = rest / nIt;
  int i = it*16 + (l & 15);
  int j = jt*32 + (l >> 4)*8 + e;
  float v = (i < I && j < J) ? src[i*ld + j] : 0.f;
  dst[f] = f2bf(v);
}

__global__ __launch_bounds__(256) void k_pack_A(
    const float* __restrict__ A00, const float* __restrict__ A01,
    const float* __restrict__ A10, const float* __restrict__ A11,
    const float* __restrict__ Ma, const float* __restrict__ Mb,
    short* __restrict__ A00pk, short* __restrict__ Mapk,
    short* __restrict__ A01pk, short* __restrict__ A10pk,
    short* __restrict__ A11pk, short* __restrict__ Mbpk) {
  int idx = blockIdx.x*256 + threadIdx.x;
  if (idx < 12288)        { packA_one(idx, A00, NA, NA, NA, 8,  A00pk); return; }
  idx -= 12288;
  if (idx < 12288)        { packA_one(idx, Ma,  NA, NA, NA, 8,  Mapk);  return; }
  idx -= 12288;
  if (idx < 40960)        { packA_one(idx, A01, NA, NB, NB, 8,  A01pk); return; }
  idx -= 40960;
  if (idx < 30720)        { packA_one(idx, A10, NB, NA, NA, 20, A10pk); return; }
  idx -= 30720;
  if (idx < 102400)       { packA_one(idx, A11, NB, NB, NB, 20, A11pk); return; }
  idx -= 102400;
  if (idx < 102400)       { packA_one(idx, Mb,  NB, NB, NB, 20, Mbpk);  return; }
}

// ---------- pack th (30 mats), theta, conv2 weights; + tconv1 weights fp32 ----------
// thpk[mat][ct][ks][lane][8]: value = th[ci][co], ci=ks*32+(l>>4)*8+e, co=ct*16+(l&15)
__global__ __launch_bounds__(256) void k_pack_th(
    const float* __restrict__ g1t1, const float* __restrict__ g1t2,
    const float* __restrict__ g1t3, const float* __restrict__ g2t1,
    const float* __restrict__ g2t2, const float* __restrict__ g2t3,
    const float* __restrict__ theta,
    const float* __restrict__ w12, const float* __restrict__ wc2,
    const float* __restrict__ w11, const float* __restrict__ wc1,
    const float* __restrict__ b11, const float* __restrict__ bc1,
    short* __restrict__ thpk, short* __restrict__ thetapk,
    short* __restrict__ W2pk, float* __restrict__ W1t, float* __restrict__ B1t) {
  int idx = blockIdx.x*256 + threadIdx.x;
  if (idx < 122880) {          // thpk: 30 mats x 4096
    int mat = idx / 4096, rem = idx % 4096;
    int ct = rem / 1024, ks = (rem / 512) & 1, l = (rem >> 3) & 63, e = rem & 7;
    int ci = ks*32 + (l >> 4)*8 + e, co = ct*16 + (l & 15);
    int layer = mat / 6, which = mat % 6;
    const float* src = which == 0 ? g1t1 : which == 1 ? g1t2 : which == 2 ? g1t3
                     : which == 3 ? g2t1 : which == 4 ? g2t2 : g2t3;
    thpk[idx] = f2bf(src[layer*4096 + ci*64 + co]);
    return;
  }
  idx -= 122880;
  if (idx < 4096) {            // thetapk
    int ct = idx / 1024, ks = (idx / 512) & 1, l = (idx >> 3) & 63, e = idx & 7;
    int ci = ks*32 + (l >> 4)*8 + e, co = ct*16 + (l & 15);
    thetapk[idx] = f2bf(theta[ci*64 + co]);
    return;
  }
  idx -= 4096;
  if (idx < 36864) {           // W2pk: [ct12][ks6][64][8]
    int ct = idx / 3072, rem = idx % 3072;
    int ks = rem / 512, l = (rem >> 3) & 63, e = rem & 7;
    int kap = ks*32 + (l >> 4)*8 + e;      // kappa = k*64 + ci
    int k = kap >> 6, ci = kap & 63;
    int cc = ct*16 + (l & 15);
    float v = (cc < 64) ? w12[cc*192 + ci*3 + k] : wc2[(cc - 64)*192 + ci*3 + k];
    W2pk[idx] = f2bf(v);
    return;
  }
  idx -= 36864;
  if (idx < 1152) {            // W1t [kk=6][cc=192] fp32
    int kk = idx / 192, cc = idx % 192;
    int k = kk >> 1, ci = kk & 1;
    W1t[idx] = (cc < 64) ? w11[cc*6 + ci*3 + k] : wc1[(cc - 64)*6 + ci*3 + k];
    return;
  }
  idx -= 1152;
  if (idx < 192) { B1t[idx] = (idx < 64) ? b11[idx] : bc1[idx - 64]; return; }
}

// ---------- temporal conv 1 (Cin=2), gated -> t1t bf16 m-major ----------
__global__ __launch_bounds__(192) void k_tconv1(const float* __restrict__ X,
                                                const float* __restrict__ W1t,
                                                const float* __restrict__ B1t,
                                                short* __restrict__ t1ta,
                                                short* __restrict__ t1tb) {
  __shared__ float xl[64];
  __shared__ float wl[6*192];
  __shared__ float bl[192];
  __shared__ float ol[T1*192];
  int bn = blockIdx.x;      // b*400 + n
  int b = bn / 400, n = bn % 400;
  int tid = threadIdx.x;
  if (tid < 64) xl[tid] = X[(size_t)bn*64 + tid];
  for (int i2 = tid; i2 < 6*192; i2 += 192) wl[i2] = W1t[i2];
  bl[tid] = B1t[tid];
  __syncthreads();
  float acc[T1];
  float bias = bl[tid];
#pragma unroll
  for (int t = 0; t < T1; ++t) acc[t] = bias;
#pragma unroll
  for (int kk = 0; kk < 6; ++kk) {
    float w = wl[kk*192 + tid];
    int k = kk >> 1, ci = kk & 1;
#pragma unroll
    for (int t = 0; t < T1; ++t) acc[t] += xl[(t + k)*2 + ci]*w;
  }
#pragma unroll
  for (int t = 0; t < T1; ++t) ol[t*192 + tid] = acc[t];
  __syncthreads();
  for (int p = tid; p < T1*64; p += 192) {
    int t = p >> 6, c = p & 63;
    float v = (ol[t*192 + 64 + c] + ol[t*192 + c])*sigmoidf_(ol[t*192 + 128 + c]);
    if (n < NA) t1ta[((size_t)b*M1 + p)*PA + n] = f2bf(v);
    else        t1tb[((size_t)b*M1 + p)*PB + (n - NA)] = f2bf(v);
  }
}

// ---------- node GEMM: S[b][i][m] = sum_j Xt[b][m][j] * Apk[j][i], bf16 MFMA ----------
// wave tile 64m x 64i, block = 2 waves (m-stacked). NM = 1 or 2 matrices.
template<int NM>
__global__ __launch_bounds__(128) void k_ngemm(const short* __restrict__ Xt, int Jpad,
                                               const short* __restrict__ Apk0,
                                               const short* __restrict__ Apk1,
                                               int nIt, int K,
                                               short* __restrict__ S0,
                                               short* __restrict__ S1o, int Ipad) {
  int lane = threadIdx.x & 63, wv = threadIdx.x >> 6;
  int ln = lane & 15, qw = lane >> 4;
  int m0 = (blockIdx.x*2 + wv)*64;
  int i0t = blockIdx.y*4;             // base i-tile (4 tiles = 64 i)
  int b = blockIdx.z;

  f32x4 acc[NM][4][4];
#pragma unroll
  for (int nmt = 0; nmt < NM; ++nmt)
#pragma unroll
    for (int mf = 0; mf < 4; ++mf)
#pragma unroll
      for (int f = 0; f < 4; ++f) acc[nmt][mf][f] = (f32x4)0.f;

  const int nks = K / 32;
  for (int ks = 0; ks < nks; ++ks) {
    short8v xa[4];
#pragma unroll
    for (int mf = 0; mf < 4; ++mf) {
      size_t xoff = ((size_t)b*M1 + m0 + mf*16 + ln)*Jpad + ks*32 + qw*8;
      xa[mf] = *(const short8v*)(Xt + xoff);
    }
    size_t abase = (((size_t)ks*nIt + i0t)*64 + lane)*8;
#pragma unroll
    for (int f = 0; f < 4; ++f) {
      short8v b0 = *(const short8v*)(Apk0 + abase + (size_t)f*512);
#pragma unroll
      for (int mf = 0; mf < 4; ++mf)
        acc[0][mf][f] = MFMA16(xa[mf], b0, acc[0][mf][f], 0, 0, 0);
      if (NM == 2) {
        short8v b1 = *(const short8v*)(Apk1 + abase + (size_t)f*512);
#pragma unroll
        for (int mf = 0; mf < 4; ++mf)
          acc[1][mf][f] = MFMA16(xa[mf], b1, acc[1][mf][f], 0, 0, 0);
      }
    }
  }
  // store: lane holds C'[m0+mf*16+qw*4+r][i0+f*16+ln], node-major out
#pragma unroll
  for (int nmt = 0; nmt < NM; ++nmt) {
    short* Sp = nmt == 0 ? S0 : S1o;
#pragma unroll
    for (int mf = 0; mf < 4; ++mf)
#pragma unroll
      for (int f = 0; f < 4; ++f) {
        int i = (i0t + f)*16 + ln;
        int m = m0 + mf*16 + qw*4;
        size_t off = ((size_t)b*Ipad + i)*M1 + m;
        short4 s4;
        s4.x = f2bf(acc[nmt][mf][f][0]);
        s4.y = f2bf(acc[nmt][mf][f][1]);
        s4.z = f2bf(acc[nmt][mf][f][2]);
        s4.w = f2bf(acc[nmt][mf][f][3]);
        *(short4*)(Sp + off) = s4;
      }
  }
}

// ---------- fused epilogue: 3 channel matmuls + gating + residual -> nu ----------
// wave handles i-pair (2 nodes) x 32 t-rows (pad) x 64 co. block = 4 waves.
__global__ __launch_bounds__(256) void k_epi(const short* __restrict__ S1,
                                             const short* __restrict__ S3,
                                             const short* __restrict__ S4,
                                             const short* __restrict__ X00,
                                             const short* __restrict__ thbase,
                                             short* __restrict__ nu,
                                             int I, int Ipad) {
  __shared__ short lth[3*4096];
  int tid = threadIdx.x;
  for (int it = tid; it < 1536; it += 256)
    ((short8v*)lth)[it] = ((const short8v*)thbase)[it];
  __syncthreads();

  int lane = tid & 63, wv = tid >> 6;
  int ln = lane & 15, qw = lane >> 4;
  int i0 = (blockIdx.x*4 + wv)*2;
  if (i0 >= I) return;
  int b = blockIdx.y;

  // A-frags: Mf = ii*2 + tf ; rows t = tf*16 + ln ; k(ci) = ks*32 + qw*8
  f32x4 u5a[4][4], u2a[4][4];
#pragma unroll
  for (int mf = 0; mf < 4; ++mf)
#pragma unroll
    for (int ct = 0; ct < 4; ++ct) { u5a[mf][ct] = (f32x4)0.f; u2a[mf][ct] = (f32x4)0.f; }

  short8v s3f[4][2], s4f[4][2];
#pragma unroll
  for (int ii = 0; ii < 2; ++ii)
#pragma unroll
    for (int tf = 0; tf < 2; ++tf)
#pragma unroll
      for (int ks = 0; ks < 2; ++ks) {
        size_t off = ((size_t)b*Ipad + i0 + ii)*M1 + (tf*16 + ln)*64 + ks*32 + qw*8;
        s3f[ii*2 + tf][ks] = *(const short8v*)(S3 + off);
        s4f[ii*2 + tf][ks] = *(const short8v*)(S4 + off);
      }
#pragma unroll
  for (int ct = 0; ct < 4; ++ct)
#pragma unroll
    for (int ks = 0; ks < 2; ++ks) {
      short8v t2 = *(const short8v*)(lth + 1*4096 + ((ct*2 + ks)*64 + lane)*8);
      short8v t3 = *(const short8v*)(lth + 2*4096 + ((ct*2 + ks)*64 + lane)*8);
#pragma unroll
      for (int mf = 0; mf < 4; ++mf) {
        u5a[mf][ct] = MFMA16(s3f[mf][ks], t2, u5a[mf][ct], 0, 0, 0);
        u5a[mf][ct] = MFMA16(s4f[mf][ks], t3, u5a[mf][ct], 0, 0, 0);
      }
    }
  short8v s1f[4][2];
#pragma unroll
  for (int ii = 0; ii < 2; ++ii)
#pragma unroll
    for (int tf = 0; tf < 2; ++tf)
#pragma unroll
      for (int ks = 0; ks < 2; ++ks) {
        size_t off = ((size_t)b*Ipad + i0 + ii)*M1 + (tf*16 + ln)*64 + ks*32 + qw*8;
        s1f[ii*2 + tf][ks] = *(const short8v*)(S1 + off);
      }
#pragma unroll
  for (int ct = 0; ct < 4; ++ct)
#pragma unroll
    for (int ks = 0; ks < 2; ++ks) {
      short8v t1m = *(const short8v*)(lth + ((ct*2 + ks)*64 + lane)*8);
#pragma unroll
      for (int mf = 0; mf < 4; ++mf)
        u2a[mf][ct] = MFMA16(s1f[mf][ks], t1m, u2a[mf][ct], 0, 0, 0);
    }
  // combine + residual + store (D: col co = ct*16+ln, row t = tf*16+qw*4+r)
#pragma unroll
  for (int ii = 0; ii < 2; ++ii) {
    int i = i0 + ii;
#pragma unroll
    for (int tf = 0; tf < 2; ++tf) {
      int mf = ii*2 + tf;
#pragma unroll
      for (int ct = 0; ct < 4; ++ct) {
        int co = ct*16 + ln;
#pragma unroll
        for (int r = 0; r < 4; ++r) {
          int t = tf*16 + qw*4 + r;
          if (t >= T1) continue;
          float u2 = fmaxf(u2a[mf][ct][r], 0.f);
          float u5 = sigmoidf_(u5a[mf][ct][r]);
          float u6 = fmaxf(0.5f*(u2 + u5), 0.f);
          size_t off = ((size_t)b*M1 + t*64 + co)*Ipad + i;
          float x0 = bf2f(X00[off]);
          nu[off] = f2bf(fmaxf(0.9f*u6 + 0.1f*x0, 0.f));
        }
      }
    }
  }
}

// ---------- theta matmul: tk[b][n][t*64+co] = relu(sum_ci u[b][t*64+ci][i]*theta) ----------
__global__ __launch_bounds__(256) void k_theta2(const short* __restrict__ u,
                                                const short* __restrict__ thetapk,
                                                short* __restrict__ tk,
                                                int I, int Ipad, int nbase) {
  __shared__ short lth[4096];
  int tid = threadIdx.x;
  for (int it = tid; it < 512; it += 256)
    ((short8v*)lth)[it] = ((const short8v*)thetapk)[it];
  __syncthreads();

  int lane = tid & 63, wv = tid >> 6;
  int ln = lane & 15, qw = lane >> 4;
  int i0 = (blockIdx.x*4 + wv)*2;
  if (i0 >= I) return;
  int b = blockIdx.y;

  f32x4 acc[4][4];
#pragma unroll
  for (int mf = 0; mf < 4; ++mf)
#pragma unroll
    for (int ct = 0; ct < 4; ++ct) acc[mf][ct] = (f32x4)0.f;

#pragma unroll
  for (int ii = 0; ii < 2; ++ii) {
    int i = i0 + ii;
    int ird = i < I ? i : (I - 1);
#pragma unroll
    for (int tf = 0; tf < 2; ++tf) {
      int t = tf*16 + ln;
#pragma unroll
      for (int ks = 0; ks < 2; ++ks) {
        short8v af;
#pragma unroll
        for (int e = 0; e < 8; ++e)
          af[e] = u[((size_t)b*M1 + t*64 + ks*32 + qw*8 + e)*Ipad + ird];
#pragma unroll
        for (int ct = 0; ct < 4; ++ct) {
          short8v bm = *(const short8v*)(lth + ((ct*2 + ks)*64 + lane)*8);
          acc[ii*2 + tf][ct] = MFMA16(af, bm, acc[ii*2 + tf][ct], 0, 0, 0);
        }
      }
    }
  }
#pragma unroll
  for (int ii = 0; ii < 2; ++ii) {
    int i = i0 + ii;
    if (i >= I) continue;
    int n = nbase + i;
#pragma unroll
    for (int tf = 0; tf < 2; ++tf)
#pragma unroll
      for (int ct = 0; ct < 4; ++ct) {
        int co = ct*16 + ln;
#pragma unroll
        for (int r = 0; r < 4; ++r) {
          int t = tf*16 + qw*4 + r;
          if (t >= T1) continue;
          tk[((size_t)b*400 + n)*TKLD + t*64 + co] =
              f2bf(fmaxf(acc[ii*2 + tf][ct][r], 0.f));
        }
      }
  }
}

// ---------- conv2 as GEMM (K=192 free-im2col) + gating -> d_out fp32 ----------
__global__ __launch_bounds__(256) void k_conv2(const short* __restrict__ tk,
                                               const short* __restrict__ W2pk,
                                               const float* __restrict__ b12,
                                               const float* __restrict__ bc2,
                                               float* __restrict__ out) {
  int tid = threadIdx.x;
  int lane = tid & 63, wv = tid >> 6;
  int ln = lane & 15, qw = lane >> 4;
  int n = blockIdx.x*4 + wv;
  int b = blockIdx.y;

  f32x4 acc[2][12];
#pragma unroll
  for (int tf = 0; tf < 2; ++tf)
#pragma unroll
    for (int ct = 0; ct < 12; ++ct) acc[tf][ct] = (f32x4)0.f;

  size_t tkb = (size_t)(b*400 + n)*TKLD;
  for (int ks = 0; ks < 6; ++ks) {
    short8v af[2];
#pragma unroll
    for (int tf = 0; tf < 2; ++tf)
      af[tf] = *(const short8v*)(tk + tkb + (tf*16 + ln)*64 + ks*32 + qw*8);
#pragma unroll
    for (int ct = 0; ct < 12; ++ct) {
      short8v bm = *(const short8v*)(W2pk + ((ct*6 + ks)*64 + lane)*8);
#pragma unroll
      for (int tf = 0; tf < 2; ++tf)
        acc[tf][ct] = MFMA16(af[tf], bm, acc[tf][ct], 0, 0, 0);
    }
  }
#pragma unroll
  for (int ct = 0; ct < 4; ++ct) {
    int co = ct*16 + ln;
    float btm = b12[co], bp = bc2[co], bq = bc2[64 + co];
#pragma unroll
    for (int tf = 0; tf < 2; ++tf)
#pragma unroll
      for (int r = 0; r < 4; ++r) {
        int t = tf*16 + qw*4 + r;
        if (t >= T2) continue;
        float tm = acc[tf][ct][r] + btm;
        float p  = acc[tf][ct + 4][r] + bp;
        float q  = acc[tf][ct + 8][r] + bq;
        out[((size_t)(b*400 + n)*T2 + t)*64 + co] = (p + tm)*sigmoidf_(q);
      }
  }
}

// ---------- batchnorm ----------
__global__ __launch_bounds__(256) void k_bn_stats(const float* __restrict__ y,
                                                  float* __restrict__ stats) {
  int n = blockIdx.x;
  int tid = threadIdx.x;
  float s = 0.f, ss = 0.f;
  for (int b = 0; b < BB; ++b) {
    const float* p = y + ((size_t)(b*400 + n))*(T2*64);
    for (int i2 = tid; i2 < T2*64; i2 += 256) {
      float v = p[i2];
      s += v; ss += v*v;
    }
  }
  __shared__ float rs[4], rss[4];
  for (int off = 32; off > 0; off >>= 1) {
    s += __shfl_down(s, off);
    ss += __shfl_down(ss, off);
  }
  if ((tid & 63) == 0) { rs[tid >> 6] = s; rss[tid >> 6] = ss; }
  __syncthreads();
  if (tid == 0) {
    float S = rs[0] + rs[1] + rs[2] + rs[3];
    float SS = rss[0] + rss[1] + rss[2] + rss[3];
    float mean = S/28672.f;
    float var = SS/28672.f - mean*mean;
    stats[n] = mean;
    stats[400 + n] = rsqrtf(var + 1e-5f);
  }
}

__global__ void k_bn_apply(float* __restrict__ y, const float* __restrict__ stats,
                           const float* __restrict__ gamma, const float* __restrict__ beta) {
  int idx = blockIdx.x*blockDim.x + threadIdx.x;
  const int total = BB*400*T2*64/4;
  for (; idx < total; idx += gridDim.x*blockDim.x) {
    int e = idx*4;
    int n = (e/(T2*64)) % 400;
    float mean = stats[n];
    float g = gamma[n]*stats[400 + n];
    float bt = beta[n];
    float4 v = ((float4*)y)[idx];
    v.x = (v.x - mean)*g + bt;
    v.y = (v.y - mean)*g + bt;
    v.z = (v.z - mean)*g + bt;
    v.w = (v.w - mean)*g + bt;
    ((float4*)y)[idx] = v;
  }
}

// ---------- host launcher ----------
extern "C" void kernel_launch(void* const* d_in, const int* in_sizes, int n_in,
                              void* d_out, int out_size, void* d_ws, size_t ws_size,
                              hipStream_t stream) {
  const float* X     = (const float*)d_in[0];
  const float* A00   = (const float*)d_in[1];
  const float* A01   = (const float*)d_in[2];
  const float* A10   = (const float*)d_in[3];
  const float* A11   = (const float*)d_in[4];
  const float* w11   = (const float*)d_in[5];
  const float* b11   = (const float*)d_in[6];
  const float* wc1   = (const float*)d_in[7];
  const float* bc1   = (const float*)d_in[8];
  const float* g1t1  = (const float*)d_in[9];
  const float* g1t2  = (const float*)d_in[10];
  const float* g1t3  = (const float*)d_in[11];
  const float* g2t1  = (const float*)d_in[12];
  const float* g2t2  = (const float*)d_in[13];
  const float* g2t3  = (const float*)d_in[14];
  const float* theta = (const float*)d_in[15];
  const float* w12   = (const float*)d_in[16];
  const float* b12   = (const float*)d_in[17];
  const float* wc2   = (const float*)d_in[18];
  const float* bc2   = (const float*)d_in[19];
  const float* gamma = (const float*)d_in[20];
  const float* beta  = (const float*)d_in[21];

  // ---- workspace layout (bf16/short units) ----
  short* ws = (short*)d_ws;
  size_t o = 0;
  short* t1ta = ws + o; o += (size_t)BB*M1*PA;          // 3,932,160
  short* t1tb = ws + o; o += (size_t)BB*M1*PB;          // 9,830,400
  short* u0   = ws + o; o += (size_t)BB*M1*PA;          // 3,932,160
  short* u1   = ws + o; o += (size_t)BB*M1*PB;          // 9,830,400
  short* slab = ws + o; o += 3*(size_t)BB*PB*M1 + 256;  // 29,491,456
  short* S1a = slab;
  short* S3a = slab + (size_t)BB*PA*M1;
  short* S4a = slab + 2*(size_t)BB*PA*M1;
  short* S1b = slab;
  short* S3b = slab + (size_t)BB*PB*M1;
  short* S4b = slab + 2*(size_t)BB*PB*M1;
  short* tk  = slab;                                    // 16*400*2176 = 13,926,400
  short* A00pk = ws + o; o += 12288;
  short* Mapk  = ws + o; o += 12288;
  short* A01pk = ws + o; o += 40960;
  short* A10pk = ws + o; o += 30720;
  short* A11pk = ws + o; o += 102400;
  short* Mbpk  = ws + o; o += 102400;
  short* thpk    = ws + o; o += 122880;
  short* thetapk = ws + o; o += 4096;
  short* W2pk    = ws + o; o += 36864;
  o = (o + 7) & ~(size_t)7;
  float* fws = (float*)(ws + o);
  float* Ma    = fws;             // 6561
  float* Mb    = Ma + 6561;       // 101761
  float* stats = Mb + 101761;     // 800
  float* W1t   = stats + 800;     // 1152
  float* B1t   = W1t + 1152;      // 192

  // ---- prep ----
  k_prep_mm<<<424, 256, 0, stream>>>(A01, A10, Ma, Mb);
  k_pack_A<<<1176, 256, 0, stream>>>(A00, A01, A10, A11, Ma, Mb,
                                     A00pk, Mapk, A01pk, A10pk, A11pk, Mbpk);
  k_pack_th<<<646, 256, 0, stream>>>(g1t1, g1t2, g1t3, g2t1, g2t2, g2t3, theta,
                                     w12, wc2, w11, wc1, b11, bc1,
                                     thpk, thetapk, W2pk, W1t, B1t);
  k_tconv1<<<BB*400, 192, 0, stream>>>(X, W1t, B1t, t1ta, t1tb);

  const short* cu0 = t1ta;
  const short* cu1 = t1tb;
  for (int l = 0; l < 5; ++l) {
    // S4a = A01 @ cu1
    k_ngemm<1><<<dim3(15, 2, BB), 128, 0, stream>>>(cu1, PB, A01pk, nullptr, 8, 320,
                                                    S4a, nullptr, PA);
    // S1a = A00 @ cu0 ; S3a = Ma @ cu0
    k_ngemm<2><<<dim3(15, 2, BB), 128, 0, stream>>>(cu0, PA, A00pk, Mapk, 8, 96,
                                                    S1a, S3a, PA);
    // epi a -> u0
    k_epi<<<dim3(11, BB), 256, 0, stream>>>(S1a, S3a, S4a, t1ta,
                                            thpk + (size_t)(l*6)*4096, u0, NA, PA);
    // S4b = A10 @ nu0
    k_ngemm<1><<<dim3(15, 5, BB), 128, 0, stream>>>(u0, PA, A10pk, nullptr, 20, 96,
                                                    S4b, nullptr, PB);
    // S1b = A11 @ cu1 ; S3b = Mb @ cu1
    k_ngemm<2><<<dim3(15, 5, BB), 128, 0, stream>>>(cu1, PB, A11pk, Mbpk, 20, 320,
                                                    S1b, S3b, PB);
    // epi b -> u1
    k_epi<<<dim3(40, BB), 256, 0, stream>>>(S1b, S3b, S4b, t1tb,
                                            thpk + (size_t)(l*6 + 3)*4096, u1, NB, PB);
    cu0 = u0;
    cu1 = u1;
  }

  // tk = relu(concat(u0,u1) @ theta), node-major bf16
  k_theta2<<<dim3(11, BB), 256, 0, stream>>>(u0, thetapk, tk, NA, PA, 0);
  k_theta2<<<dim3(40, BB), 256, 0, stream>>>(u1, thetapk, tk, NB, PB, NA);
  // conv2 + gating -> d_out fp32
  k_conv2<<<dim3(100, BB), 256, 0, stream>>>(tk, W2pk, b12, bc2, (float*)d_out);
  // batchnorm in place
  k_bn_stats<<<400, 256, 0, stream>>>((float*)d_out, stats);
  k_bn_apply<<<2048, 256, 0, stream>>>((float*)d_out, stats, gamma, beta);
}

// Round 4
// 907.864 us; speedup vs baseline: 9.5652x; 1.7070x over previous
//
#include <hip/hip_runtime.h>

// HetSTGCNBlock round 4: node-major canonical activation layout.
// Activations [b][node_pad][m=t*64+c] (node-major, coalesced everywhere);
// m-major copies [b][m][node_pad] produced by k_transpose solely for the
// node-GEMM A-operand (k=j must be lane-contiguous). Epilogue/theta/X00 all
// read/write node-major. MFMA frag layouts per guide (HW-verified).

typedef __attribute__((ext_vector_type(8))) short short8v;
typedef __attribute__((ext_vector_type(4))) float f32x4;

#define BB 16
#define NA 81
#define NB 319
#define PA 128
#define PB 320
#define M1 1920     // 30*64
#define T1 30
#define T2 28
#define TKLD 2176   // tk row pad (conv2 overreads up to 31*64+191=2175)

#define MFMA16 __builtin_amdgcn_mfma_f32_16x16x32_bf16

__device__ __forceinline__ float sigmoidf_(float x){ return 1.0f/(1.0f+__expf(-x)); }
__device__ __forceinline__ short f2bf(float f){
  unsigned u = __float_as_uint(f);
  u += 0x7FFF + ((u>>16)&1);
  return (short)(u>>16);
}
__device__ __forceinline__ float bf2f(short s){
  return __uint_as_float(((unsigned)(unsigned short)s)<<16);
}

// ---------- prep: Ma = A01@A10 (81x81), Mb = A10@A01 (319x319), fp32 ----------
__global__ __launch_bounds__(256) void k_prep_mm(const float* __restrict__ A01,
                                                 const float* __restrict__ A10,
                                                 float* __restrict__ Ma,
                                                 float* __restrict__ Mb) {
  int idx = blockIdx.x*256 + threadIdx.x;
  if (idx < NA*NA) {
    int i = idx / NA, j = idx % NA;
    float a = 0.f;
    for (int k = 0; k < NB; ++k) a += A01[i*NB + k]*A10[k*NA + j];
    Ma[idx] = a;
  } else {
    idx -= NA*NA;
    if (idx >= NB*NB) return;
    int i = idx / NB, j = idx % NB;
    float a = 0.f;
    for (int k = 0; k < NA; ++k) a += A10[i*NA + k]*A01[k*NB + j];
    Mb[idx] = a;
  }
}

// ---------- pack mixing matrices into B-frag order, bf16 ----------
__device__ __forceinline__ void packA_one(int f, const float* src, int I, int J,
                                          int ld, int nIt, short* dst) {
  int e = f & 7, l = (f >> 3) & 63, rest = f >> 9;
  int it = rest % nIt, jt = rest / nIt;
  int i = it*16 + (l & 15);
  int j = jt*32 + (l >> 4)*8 + e;
  float v = (i < I && j < J) ? src[i*ld + j] : 0.f;
  dst[f] = f2bf(v);
}

__global__ __launch_bounds__(256) void k_pack_A(
    const float* __restrict__ A00, const float* __restrict__ A01,
    const float* __restrict__ A10, const float* __restrict__ A11,
    const float* __restrict__ Ma, const float* __restrict__ Mb,
    short* __restrict__ A00pk, short* __restrict__ Mapk,
    short* __restrict__ A01pk, short* __restrict__ A10pk,
    short* __restrict__ A11pk, short* __restrict__ Mbpk) {
  int idx = blockIdx.x*256 + threadIdx.x;
  if (idx < 12288)        { packA_one(idx, A00, NA, NA, NA, 8,  A00pk); return; }
  idx -= 12288;
  if (idx < 12288)        { packA_one(idx, Ma,  NA, NA, NA, 8,  Mapk);  return; }
  idx -= 12288;
  if (idx < 40960)        { packA_one(idx, A01, NA, NB, NB, 8,  A01pk); return; }
  idx -= 40960;
  if (idx < 30720)        { packA_one(idx, A10, NB, NA, NA, 20, A10pk); return; }
  idx -= 30720;
  if (idx < 102400)       { packA_one(idx, A11, NB, NB, NB, 20, A11pk); return; }
  idx -= 102400;
  if (idx < 102400)       { packA_one(idx, Mb,  NB, NB, NB, 20, Mbpk);  return; }
}

// ---------- pack th (30 mats), theta, conv2 weights; + tconv1 weights fp32 ----------
__global__ __launch_bounds__(256) void k_pack_th(
    const float* __restrict__ g1t1, const float* __restrict__ g1t2,
    const float* __restrict__ g1t3, const float* __restrict__ g2t1,
    const float* __restrict__ g2t2, const float* __restrict__ g2t3,
    const float* __restrict__ theta,
    const float* __restrict__ w12, const float* __restrict__ wc2,
    const float* __restrict__ w11, const float* __restrict__ wc1,
    const float* __restrict__ b11, const float* __restrict__ bc1,
    short* __restrict__ thpk, short* __restrict__ thetapk,
    short* __restrict__ W2pk, float* __restrict__ W1t, float* __restrict__ B1t) {
  int idx = blockIdx.x*256 + threadIdx.x;
  if (idx < 122880) {          // thpk: 30 mats x 4096
    int mat = idx / 4096, rem = idx % 4096;
    int ct = rem / 1024, ks = (rem / 512) & 1, l = (rem >> 3) & 63, e = rem & 7;
    int ci = ks*32 + (l >> 4)*8 + e, co = ct*16 + (l & 15);
    int layer = mat / 6, which = mat % 6;
    const float* src = which == 0 ? g1t1 : which == 1 ? g1t2 : which == 2 ? g1t3
                     : which == 3 ? g2t1 : which == 4 ? g2t2 : g2t3;
    thpk[idx] = f2bf(src[layer*4096 + ci*64 + co]);
    return;
  }
  idx -= 122880;
  if (idx < 4096) {            // thetapk
    int ct = idx / 1024, ks = (idx / 512) & 1, l = (idx >> 3) & 63, e = idx & 7;
    int ci = ks*32 + (l >> 4)*8 + e, co = ct*16 + (l & 15);
    thetapk[idx] = f2bf(theta[ci*64 + co]);
    return;
  }
  idx -= 4096;
  if (idx < 36864) {           // W2pk: [ct12][ks6][64][8]
    int ct = idx / 3072, rem = idx % 3072;
    int ks = rem / 512, l = (rem >> 3) & 63, e = rem & 7;
    int kap = ks*32 + (l >> 4)*8 + e;      // kappa = k*64 + ci
    int k = kap >> 6, ci = kap & 63;
    int cc = ct*16 + (l & 15);
    float v = (cc < 64) ? w12[cc*192 + ci*3 + k] : wc2[(cc - 64)*192 + ci*3 + k];
    W2pk[idx] = f2bf(v);
    return;
  }
  idx -= 36864;
  if (idx < 1152) {            // W1t [kk=6][cc=192] fp32
    int kk = idx / 192, cc = idx % 192;
    int k = kk >> 1, ci = kk & 1;
    W1t[idx] = (cc < 64) ? w11[cc*6 + ci*3 + k] : wc1[(cc - 64)*6 + ci*3 + k];
    return;
  }
  idx -= 1152;
  if (idx < 192) { B1t[idx] = (idx < 64) ? b11[idx] : bc1[idx - 64]; return; }
}

// ---------- temporal conv 1 (Cin=2), gated -> node-major bf16 ----------
__global__ __launch_bounds__(192) void k_tconv1(const float* __restrict__ X,
                                                const float* __restrict__ W1t,
                                                const float* __restrict__ B1t,
                                                short* __restrict__ t1a,
                                                short* __restrict__ t1b) {
  __shared__ float xl[64];
  __shared__ float wl[6*192];
  __shared__ float bl[192];
  __shared__ float ol[T1*192];
  int bn = blockIdx.x;      // b*400 + n
  int b = bn / 400, n = bn % 400;
  int tid = threadIdx.x;
  if (tid < 64) xl[tid] = X[(size_t)bn*64 + tid];
  for (int i2 = tid; i2 < 6*192; i2 += 192) wl[i2] = W1t[i2];
  bl[tid] = B1t[tid];
  __syncthreads();
  float acc[T1];
  float bias = bl[tid];
#pragma unroll
  for (int t = 0; t < T1; ++t) acc[t] = bias;
#pragma unroll
  for (int kk = 0; kk < 6; ++kk) {
    float w = wl[kk*192 + tid];
    int k = kk >> 1, ci = kk & 1;
#pragma unroll
    for (int t = 0; t < T1; ++t) acc[t] += xl[(t + k)*2 + ci]*w;
  }
#pragma unroll
  for (int t = 0; t < T1; ++t) ol[t*192 + tid] = acc[t];
  __syncthreads();
  short* dst = (n < NA) ? (t1a + ((size_t)b*PA + n)*M1)
                        : (t1b + ((size_t)b*PB + (n - NA))*M1);
  for (int p = tid; p < T1*64; p += 192) {
    int t = p >> 6, c = p & 63;
    float v = (ol[t*192 + 64 + c] + ol[t*192 + c])*sigmoidf_(ol[t*192 + 128 + c]);
    dst[p] = f2bf(v);
  }
}

// ---------- transpose: node-major [b][Ipad][1920] -> m-major [b][1920][Ipad] ----------
// Writes fully coalesced (lane = node, 128B/instr). Reads lane-strided 16B
// chunks; consecutive k reuse the same 64B line via L1.
__global__ __launch_bounds__(256) void k_transpose(const short* __restrict__ src,
                                                   short* __restrict__ dst, int Ipad) {
  int lane = threadIdx.x & 63, wv = threadIdx.x >> 6;
  int n = blockIdx.x*64 + lane;
  int b = blockIdx.z;
  const short* sp = src + ((size_t)b*Ipad + n)*M1;
  int mbase = (blockIdx.y*4 + wv)*120;
  for (int k = 0; k < 120; k += 8) {
    int m = mbase + k;
    short8v v = *(const short8v*)(sp + m);
#pragma unroll
    for (int e = 0; e < 8; ++e)
      dst[((size_t)b*M1 + m + e)*Ipad + n] = v[e];
  }
}

// ---------- node GEMM: S[b][i][m] = sum_j XT[b][m][j] * Apk[j][i], bf16 MFMA ----------
template<int NM>
__global__ __launch_bounds__(128) void k_ngemm(const short* __restrict__ Xt, int Jpad,
                                               const short* __restrict__ Apk0,
                                               const short* __restrict__ Apk1,
                                               int nIt, int K,
                                               short* __restrict__ S0,
                                               short* __restrict__ S1o, int Ipad) {
  int lane = threadIdx.x & 63, wv = threadIdx.x >> 6;
  int ln = lane & 15, qw = lane >> 4;
  int m0 = (blockIdx.x*2 + wv)*64;
  int i0t = blockIdx.y*4;
  int b = blockIdx.z;

  f32x4 acc[NM][4][4];
#pragma unroll
  for (int nmt = 0; nmt < NM; ++nmt)
#pragma unroll
    for (int mf = 0; mf < 4; ++mf)
#pragma unroll
      for (int f = 0; f < 4; ++f) acc[nmt][mf][f] = (f32x4)0.f;

  const int nks = K / 32;
  for (int ks = 0; ks < nks; ++ks) {
    short8v xa[4];
#pragma unroll
    for (int mf = 0; mf < 4; ++mf) {
      size_t xoff = ((size_t)b*M1 + m0 + mf*16 + ln)*Jpad + ks*32 + qw*8;
      xa[mf] = *(const short8v*)(Xt + xoff);
    }
    size_t abase = (((size_t)ks*nIt + i0t)*64 + lane)*8;
#pragma unroll
    for (int f = 0; f < 4; ++f) {
      short8v b0 = *(const short8v*)(Apk0 + abase + (size_t)f*512);
#pragma unroll
      for (int mf = 0; mf < 4; ++mf)
        acc[0][mf][f] = MFMA16(xa[mf], b0, acc[0][mf][f], 0, 0, 0);
      if (NM == 2) {
        short8v b1 = *(const short8v*)(Apk1 + abase + (size_t)f*512);
#pragma unroll
        for (int mf = 0; mf < 4; ++mf)
          acc[1][mf][f] = MFMA16(xa[mf], b1, acc[1][mf][f], 0, 0, 0);
      }
    }
  }
#pragma unroll
  for (int nmt = 0; nmt < NM; ++nmt) {
    short* Sp = nmt == 0 ? S0 : S1o;
#pragma unroll
    for (int mf = 0; mf < 4; ++mf)
#pragma unroll
      for (int f = 0; f < 4; ++f) {
        int i = (i0t + f)*16 + ln;
        int m = m0 + mf*16 + qw*4;
        size_t off = ((size_t)b*Ipad + i)*M1 + m;
        short4 s4;
        s4.x = f2bf(acc[nmt][mf][f][0]);
        s4.y = f2bf(acc[nmt][mf][f][1]);
        s4.z = f2bf(acc[nmt][mf][f][2]);
        s4.w = f2bf(acc[nmt][mf][f][3]);
        *(short4*)(Sp + off) = s4;
      }
  }
}

// ---------- fused epilogue: 3 channel matmuls + gating + residual -> nu (node-major) ----------
__global__ __launch_bounds__(256) void k_epi(const short* __restrict__ S1,
                                             const short* __restrict__ S3,
                                             const short* __restrict__ S4,
                                             const short* __restrict__ X00,
                                             const short* __restrict__ thbase,
                                             short* __restrict__ nu,
                                             int I, int Ipad) {
  __shared__ short lth[3*4096];
  int tid = threadIdx.x;
  for (int it = tid; it < 1536; it += 256)
    ((short8v*)lth)[it] = ((const short8v*)thbase)[it];
  __syncthreads();

  int lane = tid & 63, wv = tid >> 6;
  int ln = lane & 15, qw = lane >> 4;
  int i0 = (blockIdx.x*4 + wv)*2;
  if (i0 >= I) return;
  int b = blockIdx.y;

  f32x4 u5a[4][4], u2a[4][4];
#pragma unroll
  for (int mf = 0; mf < 4; ++mf)
#pragma unroll
    for (int ct = 0; ct < 4; ++ct) { u5a[mf][ct] = (f32x4)0.f; u2a[mf][ct] = (f32x4)0.f; }

  short8v s3f[4][2], s4f[4][2];
#pragma unroll
  for (int ii = 0; ii < 2; ++ii)
#pragma unroll
    for (int tf = 0; tf < 2; ++tf)
#pragma unroll
      for (int ks = 0; ks < 2; ++ks) {
        size_t off = ((size_t)b*Ipad + i0 + ii)*M1 + (tf*16 + ln)*64 + ks*32 + qw*8;
        s3f[ii*2 + tf][ks] = *(const short8v*)(S3 + off);
        s4f[ii*2 + tf][ks] = *(const short8v*)(S4 + off);
      }
#pragma unroll
  for (int ct = 0; ct < 4; ++ct)
#pragma unroll
    for (int ks = 0; ks < 2; ++ks) {
      short8v t2 = *(const short8v*)(lth + 1*4096 + ((ct*2 + ks)*64 + lane)*8);
      short8v t3 = *(const short8v*)(lth + 2*4096 + ((ct*2 + ks)*64 + lane)*8);
#pragma unroll
      for (int mf = 0; mf < 4; ++mf) {
        u5a[mf][ct] = MFMA16(s3f[mf][ks], t2, u5a[mf][ct], 0, 0, 0);
        u5a[mf][ct] = MFMA16(s4f[mf][ks], t3, u5a[mf][ct], 0, 0, 0);
      }
    }
  short8v s1f[4][2];
#pragma unroll
  for (int ii = 0; ii < 2; ++ii)
#pragma unroll
    for (int tf = 0; tf < 2; ++tf)
#pragma unroll
      for (int ks = 0; ks < 2; ++ks) {
        size_t off = ((size_t)b*Ipad + i0 + ii)*M1 + (tf*16 + ln)*64 + ks*32 + qw*8;
        s1f[ii*2 + tf][ks] = *(const short8v*)(S1 + off);
      }
#pragma unroll
  for (int ct = 0; ct < 4; ++ct)
#pragma unroll
    for (int ks = 0; ks < 2; ++ks) {
      short8v t1m = *(const short8v*)(lth + ((ct*2 + ks)*64 + lane)*8);
#pragma unroll
      for (int mf = 0; mf < 4; ++mf)
        u2a[mf][ct] = MFMA16(s1f[mf][ks], t1m, u2a[mf][ct], 0, 0, 0);
    }
  // combine + residual + store node-major (D: col co=ct*16+ln, row t=tf*16+qw*4+r)
#pragma unroll
  for (int ii = 0; ii < 2; ++ii) {
    int i = i0 + ii;
#pragma unroll
    for (int tf = 0; tf < 2; ++tf) {
      int mf = ii*2 + tf;
#pragma unroll
      for (int ct = 0; ct < 4; ++ct) {
        int co = ct*16 + ln;
#pragma unroll
        for (int r = 0; r < 4; ++r) {
          int t = tf*16 + qw*4 + r;
          if (t >= T1) continue;
          float u2 = fmaxf(u2a[mf][ct][r], 0.f);
          float u5 = sigmoidf_(u5a[mf][ct][r]);
          float u6 = fmaxf(0.5f*(u2 + u5), 0.f);
          size_t off = ((size_t)b*Ipad + i)*M1 + t*64 + co;
          float x0 = bf2f(X00[off]);
          nu[off] = f2bf(fmaxf(0.9f*u6 + 0.1f*x0, 0.f));
        }
      }
    }
  }
}

// ---------- theta matmul (node-major in/out) ----------
__global__ __launch_bounds__(256) void k_theta2(const short* __restrict__ u,
                                                const short* __restrict__ thetapk,
                                                short* __restrict__ tk,
                                                int I, int Ipad, int nbase) {
  __shared__ short lth[4096];
  int tid = threadIdx.x;
  for (int it = tid; it < 512; it += 256)
    ((short8v*)lth)[it] = ((const short8v*)thetapk)[it];
  __syncthreads();

  int lane = tid & 63, wv = tid >> 6;
  int ln = lane & 15, qw = lane >> 4;
  int i0 = (blockIdx.x*4 + wv)*2;
  if (i0 >= I) return;
  int b = blockIdx.y;

  f32x4 acc[4][4];
#pragma unroll
  for (int mf = 0; mf < 4; ++mf)
#pragma unroll
    for (int ct = 0; ct < 4; ++ct) acc[mf][ct] = (f32x4)0.f;

#pragma unroll
  for (int ii = 0; ii < 2; ++ii) {
#pragma unroll
    for (int tf = 0; tf < 2; ++tf) {
#pragma unroll
      for (int ks = 0; ks < 2; ++ks) {
        size_t off = ((size_t)b*Ipad + i0 + ii)*M1 + (tf*16 + ln)*64 + ks*32 + qw*8;
        short8v af = *(const short8v*)(u + off);
#pragma unroll
        for (int ct = 0; ct < 4; ++ct) {
          short8v bm = *(const short8v*)(lth + ((ct*2 + ks)*64 + lane)*8);
          acc[ii*2 + tf][ct] = MFMA16(af, bm, acc[ii*2 + tf][ct], 0, 0, 0);
        }
      }
    }
  }
#pragma unroll
  for (int ii = 0; ii < 2; ++ii) {
    int i = i0 + ii;
    if (i >= I) continue;
    int n = nbase + i;
#pragma unroll
    for (int tf = 0; tf < 2; ++tf)
#pragma unroll
      for (int ct = 0; ct < 4; ++ct) {
        int co = ct*16 + ln;
#pragma unroll
        for (int r = 0; r < 4; ++r) {
          int t = tf*16 + qw*4 + r;
          if (t >= T1) continue;
          tk[((size_t)b*400 + n)*TKLD + t*64 + co] =
              f2bf(fmaxf(acc[ii*2 + tf][ct][r], 0.f));
        }
      }
  }
}

// ---------- conv2 as GEMM (K=192 free-im2col) + gating -> d_out fp32 ----------
__global__ __launch_bounds__(256) void k_conv2(const short* __restrict__ tk,
                                               const short* __restrict__ W2pk,
                                               const float* __restrict__ b12,
                                               const float* __restrict__ bc2,
                                               float* __restrict__ out) {
  int tid = threadIdx.x;
  int lane = tid & 63, wv = tid >> 6;
  int ln = lane & 15, qw = lane >> 4;
  int n = blockIdx.x*4 + wv;
  int b = blockIdx.y;

  f32x4 acc[2][12];
#pragma unroll
  for (int tf = 0; tf < 2; ++tf)
#pragma unroll
    for (int ct = 0; ct < 12; ++ct) acc[tf][ct] = (f32x4)0.f;

  size_t tkb = (size_t)(b*400 + n)*TKLD;
  for (int ks = 0; ks < 6; ++ks) {
    short8v af[2];
#pragma unroll
    for (int tf = 0; tf < 2; ++tf)
      af[tf] = *(const short8v*)(tk + tkb + (tf*16 + ln)*64 + ks*32 + qw*8);
#pragma unroll
    for (int ct = 0; ct < 12; ++ct) {
      short8v bm = *(const short8v*)(W2pk + ((ct*6 + ks)*64 + lane)*8);
#pragma unroll
      for (int tf = 0; tf < 2; ++tf)
        acc[tf][ct] = MFMA16(af[tf], bm, acc[tf][ct], 0, 0, 0);
    }
  }
#pragma unroll
  for (int ct = 0; ct < 4; ++ct) {
    int co = ct*16 + ln;
    float btm = b12[co], bp = bc2[co], bq = bc2[64 + co];
#pragma unroll
    for (int tf = 0; tf < 2; ++tf)
#pragma unroll
      for (int r = 0; r < 4; ++r) {
        int t = tf*16 + qw*4 + r;
        if (t >= T2) continue;
        float tm = acc[tf][ct][r] + btm;
        float p  = acc[tf][ct + 4][r] + bp;
        float q  = acc[tf][ct + 8][r] + bq;
        out[((size_t)(b*400 + n)*T2 + t)*64 + co] = (p + tm)*sigmoidf_(q);
      }
  }
}

// ---------- batchnorm ----------
__global__ __launch_bounds__(256) void k_bn_stats(const float* __restrict__ y,
                                                  float* __restrict__ stats) {
  int n = blockIdx.x;
  int tid = threadIdx.x;
  float s = 0.f, ss = 0.f;
  for (int b = 0; b < BB; ++b) {
    const float* p = y + ((size_t)(b*400 + n))*(T2*64);
    for (int i2 = tid; i2 < T2*64; i2 += 256) {
      float v = p[i2];
      s += v; ss += v*v;
    }
  }
  __shared__ float rs[4], rss[4];
  for (int off = 32; off > 0; off >>= 1) {
    s += __shfl_down(s, off);
    ss += __shfl_down(ss, off);
  }
  if ((tid & 63) == 0) { rs[tid >> 6] = s; rss[tid >> 6] = ss; }
  __syncthreads();
  if (tid == 0) {
    float S = rs[0] + rs[1] + rs[2] + rs[3];
    float SS = rss[0] + rss[1] + rss[2] + rss[3];
    float mean = S/28672.f;
    float var = SS/28672.f - mean*mean;
    stats[n] = mean;
    stats[400 + n] = rsqrtf(var + 1e-5f);
  }
}

__global__ void k_bn_apply(float* __restrict__ y, const float* __restrict__ stats,
                           const float* __restrict__ gamma, const float* __restrict__ beta) {
  int idx = blockIdx.x*blockDim.x + threadIdx.x;
  const int total = BB*400*T2*64/4;
  for (; idx < total; idx += gridDim.x*blockDim.x) {
    int e = idx*4;
    int n = (e/(T2*64)) % 400;
    float mean = stats[n];
    float g = gamma[n]*stats[400 + n];
    float bt = beta[n];
    float4 v = ((float4*)y)[idx];
    v.x = (v.x - mean)*g + bt;
    v.y = (v.y - mean)*g + bt;
    v.z = (v.z - mean)*g + bt;
    v.w = (v.w - mean)*g + bt;
    ((float4*)y)[idx] = v;
  }
}

// ---------- host launcher ----------
extern "C" void kernel_launch(void* const* d_in, const int* in_sizes, int n_in,
                              void* d_out, int out_size, void* d_ws, size_t ws_size,
                              hipStream_t stream) {
  const float* X     = (const float*)d_in[0];
  const float* A00   = (const float*)d_in[1];
  const float* A01   = (const float*)d_in[2];
  const float* A10   = (const float*)d_in[3];
  const float* A11   = (const float*)d_in[4];
  const float* w11   = (const float*)d_in[5];
  const float* b11   = (const float*)d_in[6];
  const float* wc1   = (const float*)d_in[7];
  const float* bc1   = (const float*)d_in[8];
  const float* g1t1  = (const float*)d_in[9];
  const float* g1t2  = (const float*)d_in[10];
  const float* g1t3  = (const float*)d_in[11];
  const float* g2t1  = (const float*)d_in[12];
  const float* g2t2  = (const float*)d_in[13];
  const float* g2t3  = (const float*)d_in[14];
  const float* theta = (const float*)d_in[15];
  const float* w12   = (const float*)d_in[16];
  const float* b12   = (const float*)d_in[17];
  const float* wc2   = (const float*)d_in[18];
  const float* bc2   = (const float*)d_in[19];
  const float* gamma = (const float*)d_in[20];
  const float* beta  = (const float*)d_in[21];

  // ---- workspace layout (bf16/short units) ----
  short* ws = (short*)d_ws;
  size_t o = 0;
  short* t1a  = ws + o; o += (size_t)BB*PA*M1;          // node-major t1 (a) 3,932,160
  short* t1b  = ws + o; o += (size_t)BB*PB*M1;          // node-major t1 (b) 9,830,400
  short* u0   = ws + o; o += (size_t)BB*PA*M1;          // node-major u0
  short* u1   = ws + o; o += (size_t)BB*PB*M1;          // node-major u1
  short* uaT  = ws + o; o += (size_t)BB*M1*PA;          // m-major (a-side ngemm input)
  short* ubT  = ws + o; o += (size_t)BB*M1*PB;          // m-major (b-side ngemm input)
  short* slab = ws + o; o += 3*(size_t)BB*PB*M1 + 256;  // S buffers / tk
  short* S1a = slab;
  short* S3a = slab + (size_t)BB*PA*M1;
  short* S4a = slab + 2*(size_t)BB*PA*M1;
  short* S1b = slab;
  short* S3b = slab + (size_t)BB*PB*M1;
  short* S4b = slab + 2*(size_t)BB*PB*M1;
  short* tk  = slab;                                    // 16*400*2176
  short* A00pk = ws + o; o += 12288;
  short* Mapk  = ws + o; o += 12288;
  short* A01pk = ws + o; o += 40960;
  short* A10pk = ws + o; o += 30720;
  short* A11pk = ws + o; o += 102400;
  short* Mbpk  = ws + o; o += 102400;
  short* thpk    = ws + o; o += 122880;
  short* thetapk = ws + o; o += 4096;
  short* W2pk    = ws + o; o += 36864;
  o = (o + 7) & ~(size_t)7;
  float* fws = (float*)(ws + o);
  float* Ma    = fws;
  float* Mb    = Ma + 6561;
  float* stats = Mb + 101761;
  float* W1t   = stats + 800;
  float* B1t   = W1t + 1152;

  // ---- prep ----
  k_prep_mm<<<424, 256, 0, stream>>>(A01, A10, Ma, Mb);
  k_pack_A<<<1176, 256, 0, stream>>>(A00, A01, A10, A11, Ma, Mb,
                                     A00pk, Mapk, A01pk, A10pk, A11pk, Mbpk);
  k_pack_th<<<646, 256, 0, stream>>>(g1t1, g1t2, g1t3, g2t1, g2t2, g2t3, theta,
                                     w12, wc2, w11, wc1, b11, bc1,
                                     thpk, thetapk, W2pk, W1t, B1t);
  k_tconv1<<<BB*400, 192, 0, stream>>>(X, W1t, B1t, t1a, t1b);
  // initial m-major copies for layer-0 ngemms
  k_transpose<<<dim3(PA/64, 4, BB), 256, 0, stream>>>(t1a, uaT, PA);
  k_transpose<<<dim3(PB/64, 4, BB), 256, 0, stream>>>(t1b, ubT, PB);

  for (int l = 0; l < 5; ++l) {
    // S4a = A01 @ u1T
    k_ngemm<1><<<dim3(15, 2, BB), 128, 0, stream>>>(ubT, PB, A01pk, nullptr, 8, 320,
                                                    S4a, nullptr, PA);
    // S1a = A00 @ u0T ; S3a = Ma @ u0T
    k_ngemm<2><<<dim3(15, 2, BB), 128, 0, stream>>>(uaT, PA, A00pk, Mapk, 8, 96,
                                                    S1a, S3a, PA);
    // epi a -> u0 (node-major)
    k_epi<<<dim3(11, BB), 256, 0, stream>>>(S1a, S3a, S4a, t1a,
                                            thpk + (size_t)(l*6)*4096, u0, NA, PA);
    // u0 -> uaT (m-major) for S4b ngemm
    k_transpose<<<dim3(PA/64, 4, BB), 256, 0, stream>>>(u0, uaT, PA);
    // S4b = A10 @ u0T
    k_ngemm<1><<<dim3(15, 5, BB), 128, 0, stream>>>(uaT, PA, A10pk, nullptr, 20, 96,
                                                    S4b, nullptr, PB);
    // S1b = A11 @ u1T ; S3b = Mb @ u1T
    k_ngemm<2><<<dim3(15, 5, BB), 128, 0, stream>>>(ubT, PB, A11pk, Mbpk, 20, 320,
                                                    S1b, S3b, PB);
    // epi b -> u1 (node-major)
    k_epi<<<dim3(40, BB), 256, 0, stream>>>(S1b, S3b, S4b, t1b,
                                            thpk + (size_t)(l*6 + 3)*4096, u1, NB, PB);
    // u1 -> ubT (needed by next layer's ngemms)
    if (l < 4)
      k_transpose<<<dim3(PB/64, 4, BB), 256, 0, stream>>>(u1, ubT, PB);
  }

  // tk = relu(concat(u0,u1) @ theta) — reads node-major u directly
  k_theta2<<<dim3(11, BB), 256, 0, stream>>>(u0, thetapk, tk, NA, PA, 0);
  k_theta2<<<dim3(40, BB), 256, 0, stream>>>(u1, thetapk, tk, NB, PB, NA);
  // conv2 + gating -> d_out fp32
  k_conv2<<<dim3(100, BB), 256, 0, stream>>>(tk, W2pk, b12, bc2, (float*)d_out);
  // batchnorm in place
  k_bn_stats<<<400, 256, 0, stream>>>((float*)d_out, stats);
  k_bn_apply<<<2048, 256, 0, stream>>>((float*)d_out, stats, gamma, beta);
}

// Round 5
// 822.691 us; speedup vs baseline: 10.5555x; 1.1035x over previous
//
#include <hip/hip_runtime.h>

// HetSTGCNBlock round 5: occupancy pass.
// - theta+conv2 fused (block per node, 4 waves, LDS row-pad 72 -> aligned b128)
// - ngemm wave i-tile 32 (FT template): acc 64 regs, 2x grid.y
// - epi 1 node/wave
// Layouts identical to round 4 (node-major activations; m-major copies for
// ngemm A-operand via k_transpose; packed B-frags for all static matrices).

typedef __attribute__((ext_vector_type(8))) short short8v;
typedef __attribute__((ext_vector_type(4))) float f32x4;

#define BB 16
#define NA 81
#define NB 319
#define PA 128
#define PB 320
#define M1 1920     // 30*64
#define T1 30
#define T2 28

#define MFMA16 __builtin_amdgcn_mfma_f32_16x16x32_bf16

__device__ __forceinline__ float sigmoidf_(float x){ return 1.0f/(1.0f+__expf(-x)); }
__device__ __forceinline__ short f2bf(float f){
  unsigned u = __float_as_uint(f);
  u += 0x7FFF + ((u>>16)&1);
  return (short)(u>>16);
}
__device__ __forceinline__ float bf2f(short s){
  return __uint_as_float(((unsigned)(unsigned short)s)<<16);
}

// ---------- prep: Ma = A01@A10 (81x81), Mb = A10@A01 (319x319), fp32 ----------
__global__ __launch_bounds__(256) void k_prep_mm(const float* __restrict__ A01,
                                                 const float* __restrict__ A10,
                                                 float* __restrict__ Ma,
                                                 float* __restrict__ Mb) {
  int idx = blockIdx.x*256 + threadIdx.x;
  if (idx < NA*NA) {
    int i = idx / NA, j = idx % NA;
    float a = 0.f;
    for (int k = 0; k < NB; ++k) a += A01[i*NB + k]*A10[k*NA + j];
    Ma[idx] = a;
  } else {
    idx -= NA*NA;
    if (idx >= NB*NB) return;
    int i = idx / NB, j = idx % NB;
    float a = 0.f;
    for (int k = 0; k < NA; ++k) a += A10[i*NA + k]*A01[k*NB + j];
    Mb[idx] = a;
  }
}

// ---------- pack mixing matrices into B-frag order, bf16 ----------
__device__ __forceinline__ void packA_one(int f, const float* src, int I, int J,
                                          int ld, int nIt, short* dst) {
  int e = f & 7, l = (f >> 3) & 63, rest = f >> 9;
  int it = rest % nIt, jt = rest / nIt;
  int i = it*16 + (l & 15);
  int j = jt*32 + (l >> 4)*8 + e;
  float v = (i < I && j < J) ? src[i*ld + j] : 0.f;
  dst[f] = f2bf(v);
}

__global__ __launch_bounds__(256) void k_pack_A(
    const float* __restrict__ A00, const float* __restrict__ A01,
    const float* __restrict__ A10, const float* __restrict__ A11,
    const float* __restrict__ Ma, const float* __restrict__ Mb,
    short* __restrict__ A00pk, short* __restrict__ Mapk,
    short* __restrict__ A01pk, short* __restrict__ A10pk,
    short* __restrict__ A11pk, short* __restrict__ Mbpk) {
  int idx = blockIdx.x*256 + threadIdx.x;
  if (idx < 12288)        { packA_one(idx, A00, NA, NA, NA, 8,  A00pk); return; }
  idx -= 12288;
  if (idx < 12288)        { packA_one(idx, Ma,  NA, NA, NA, 8,  Mapk);  return; }
  idx -= 12288;
  if (idx < 40960)        { packA_one(idx, A01, NA, NB, NB, 8,  A01pk); return; }
  idx -= 40960;
  if (idx < 30720)        { packA_one(idx, A10, NB, NA, NA, 20, A10pk); return; }
  idx -= 30720;
  if (idx < 102400)       { packA_one(idx, A11, NB, NB, NB, 20, A11pk); return; }
  idx -= 102400;
  if (idx < 102400)       { packA_one(idx, Mb,  NB, NB, NB, 20, Mbpk);  return; }
}

// ---------- pack th (30 mats), theta, conv2 weights; + tconv1 weights fp32 ----------
__global__ __launch_bounds__(256) void k_pack_th(
    const float* __restrict__ g1t1, const float* __restrict__ g1t2,
    const float* __restrict__ g1t3, const float* __restrict__ g2t1,
    const float* __restrict__ g2t2, const float* __restrict__ g2t3,
    const float* __restrict__ theta,
    const float* __restrict__ w12, const float* __restrict__ wc2,
    const float* __restrict__ w11, const float* __restrict__ wc1,
    const float* __restrict__ b11, const float* __restrict__ bc1,
    short* __restrict__ thpk, short* __restrict__ thetapk,
    short* __restrict__ W2pk, float* __restrict__ W1t, float* __restrict__ B1t) {
  int idx = blockIdx.x*256 + threadIdx.x;
  if (idx < 122880) {          // thpk: 30 mats x 4096
    int mat = idx / 4096, rem = idx % 4096;
    int ct = rem / 1024, ks = (rem / 512) & 1, l = (rem >> 3) & 63, e = rem & 7;
    int ci = ks*32 + (l >> 4)*8 + e, co = ct*16 + (l & 15);
    int layer = mat / 6, which = mat % 6;
    const float* src = which == 0 ? g1t1 : which == 1 ? g1t2 : which == 2 ? g1t3
                     : which == 3 ? g2t1 : which == 4 ? g2t2 : g2t3;
    thpk[idx] = f2bf(src[layer*4096 + ci*64 + co]);
    return;
  }
  idx -= 122880;
  if (idx < 4096) {            // thetapk
    int ct = idx / 1024, ks = (idx / 512) & 1, l = (idx >> 3) & 63, e = idx & 7;
    int ci = ks*32 + (l >> 4)*8 + e, co = ct*16 + (l & 15);
    thetapk[idx] = f2bf(theta[ci*64 + co]);
    return;
  }
  idx -= 4096;
  if (idx < 36864) {           // W2pk: [ct12][ks6][64][8]
    int ct = idx / 3072, rem = idx % 3072;
    int ks = rem / 512, l = (rem >> 3) & 63, e = rem & 7;
    int kap = ks*32 + (l >> 4)*8 + e;      // kappa = k*64 + ci
    int k = kap >> 6, ci = kap & 63;
    int cc = ct*16 + (l & 15);
    float v = (cc < 64) ? w12[cc*192 + ci*3 + k] : wc2[(cc - 64)*192 + ci*3 + k];
    W2pk[idx] = f2bf(v);
    return;
  }
  idx -= 36864;
  if (idx < 1152) {            // W1t [kk=6][cc=192] fp32
    int kk = idx / 192, cc = idx % 192;
    int k = kk >> 1, ci = kk & 1;
    W1t[idx] = (cc < 64) ? w11[cc*6 + ci*3 + k] : wc1[(cc - 64)*6 + ci*3 + k];
    return;
  }
  idx -= 1152;
  if (idx < 192) { B1t[idx] = (idx < 64) ? b11[idx] : bc1[idx - 64]; return; }
}

// ---------- temporal conv 1 (Cin=2), gated -> node-major bf16 ----------
__global__ __launch_bounds__(192) void k_tconv1(const float* __restrict__ X,
                                                const float* __restrict__ W1t,
                                                const float* __restrict__ B1t,
                                                short* __restrict__ t1a,
                                                short* __restrict__ t1b) {
  __shared__ float xl[64];
  __shared__ float wl[6*192];
  __shared__ float bl[192];
  __shared__ float ol[T1*192];
  int bn = blockIdx.x;      // b*400 + n
  int b = bn / 400, n = bn % 400;
  int tid = threadIdx.x;
  if (tid < 64) xl[tid] = X[(size_t)bn*64 + tid];
  for (int i2 = tid; i2 < 6*192; i2 += 192) wl[i2] = W1t[i2];
  bl[tid] = B1t[tid];
  __syncthreads();
  float acc[T1];
  float bias = bl[tid];
#pragma unroll
  for (int t = 0; t < T1; ++t) acc[t] = bias;
#pragma unroll
  for (int kk = 0; kk < 6; ++kk) {
    float w = wl[kk*192 + tid];
    int k = kk >> 1, ci = kk & 1;
#pragma unroll
    for (int t = 0; t < T1; ++t) acc[t] += xl[(t + k)*2 + ci]*w;
  }
#pragma unroll
  for (int t = 0; t < T1; ++t) ol[t*192 + tid] = acc[t];
  __syncthreads();
  short* dst = (n < NA) ? (t1a + ((size_t)b*PA + n)*M1)
                        : (t1b + ((size_t)b*PB + (n - NA))*M1);
  for (int p = tid; p < T1*64; p += 192) {
    int t = p >> 6, c = p & 63;
    float v = (ol[t*192 + 64 + c] + ol[t*192 + c])*sigmoidf_(ol[t*192 + 128 + c]);
    dst[p] = f2bf(v);
  }
}

// ---------- transpose: node-major [b][Ipad][1920] -> m-major [b][1920][Ipad] ----------
__global__ __launch_bounds__(256) void k_transpose(const short* __restrict__ src,
                                                   short* __restrict__ dst, int Ipad) {
  int lane = threadIdx.x & 63, wv = threadIdx.x >> 6;
  int n = blockIdx.x*64 + lane;
  int b = blockIdx.z;
  const short* sp = src + ((size_t)b*Ipad + n)*M1;
  int mbase = (blockIdx.y*4 + wv)*120;
  for (int k = 0; k < 120; k += 8) {
    int m = mbase + k;
    short8v v = *(const short8v*)(sp + m);
#pragma unroll
    for (int e = 0; e < 8; ++e)
      dst[((size_t)b*M1 + m + e)*Ipad + n] = v[e];
  }
}

// ---------- node GEMM: S[b][i][m] = sum_j XT[b][m][j] * Apk[j][i], bf16 MFMA ----------
// wave tile: 64m x (FT*16)i ; block = 2 waves m-stacked.
template<int NM, int FT>
__global__ __launch_bounds__(128) void k_ngemm(const short* __restrict__ Xt, int Jpad,
                                               const short* __restrict__ Apk0,
                                               const short* __restrict__ Apk1,
                                               int nIt, int K,
                                               short* __restrict__ S0,
                                               short* __restrict__ S1o, int Ipad) {
  int lane = threadIdx.x & 63, wv = threadIdx.x >> 6;
  int ln = lane & 15, qw = lane >> 4;
  int m0 = (blockIdx.x*2 + wv)*64;
  int i0t = blockIdx.y*FT;
  int b = blockIdx.z;

  f32x4 acc[NM][4][FT];
#pragma unroll
  for (int nmt = 0; nmt < NM; ++nmt)
#pragma unroll
    for (int mf = 0; mf < 4; ++mf)
#pragma unroll
      for (int f = 0; f < FT; ++f) acc[nmt][mf][f] = (f32x4)0.f;

  const int nks = K / 32;
  for (int ks = 0; ks < nks; ++ks) {
    short8v xa[4];
#pragma unroll
    for (int mf = 0; mf < 4; ++mf) {
      size_t xoff = ((size_t)b*M1 + m0 + mf*16 + ln)*Jpad + ks*32 + qw*8;
      xa[mf] = *(const short8v*)(Xt + xoff);
    }
    size_t abase = (((size_t)ks*nIt + i0t)*64 + lane)*8;
#pragma unroll
    for (int f = 0; f < FT; ++f) {
      short8v b0 = *(const short8v*)(Apk0 + abase + (size_t)f*512);
#pragma unroll
      for (int mf = 0; mf < 4; ++mf)
        acc[0][mf][f] = MFMA16(xa[mf], b0, acc[0][mf][f], 0, 0, 0);
      if (NM == 2) {
        short8v b1 = *(const short8v*)(Apk1 + abase + (size_t)f*512);
#pragma unroll
        for (int mf = 0; mf < 4; ++mf)
          acc[1][mf][f] = MFMA16(xa[mf], b1, acc[1][mf][f], 0, 0, 0);
      }
    }
  }
#pragma unroll
  for (int nmt = 0; nmt < NM; ++nmt) {
    short* Sp = nmt == 0 ? S0 : S1o;
#pragma unroll
    for (int mf = 0; mf < 4; ++mf)
#pragma unroll
      for (int f = 0; f < FT; ++f) {
        int i = (i0t + f)*16 + ln;
        int m = m0 + mf*16 + qw*4;
        size_t off = ((size_t)b*Ipad + i)*M1 + m;
        short4 s4;
        s4.x = f2bf(acc[nmt][mf][f][0]);
        s4.y = f2bf(acc[nmt][mf][f][1]);
        s4.z = f2bf(acc[nmt][mf][f][2]);
        s4.w = f2bf(acc[nmt][mf][f][3]);
        *(short4*)(Sp + off) = s4;
      }
  }
}

// ---------- fused epilogue: 3 channel matmuls + gating + residual (1 node/wave) ----------
__global__ __launch_bounds__(256) void k_epi(const short* __restrict__ S1,
                                             const short* __restrict__ S3,
                                             const short* __restrict__ S4,
                                             const short* __restrict__ X00,
                                             const short* __restrict__ thbase,
                                             short* __restrict__ nu,
                                             int I, int Ipad) {
  __shared__ short lth[3*4096];
  int tid = threadIdx.x;
  for (int it = tid; it < 1536; it += 256)
    ((short8v*)lth)[it] = ((const short8v*)thbase)[it];
  __syncthreads();

  int lane = tid & 63, wv = tid >> 6;
  int ln = lane & 15, qw = lane >> 4;
  int i = blockIdx.x*4 + wv;
  if (i >= I) return;
  int b = blockIdx.y;
  size_t nbase = ((size_t)b*Ipad + i)*M1;

  f32x4 u5a[2][4], u2a[2][4];
#pragma unroll
  for (int tf = 0; tf < 2; ++tf)
#pragma unroll
    for (int ct = 0; ct < 4; ++ct) { u5a[tf][ct] = (f32x4)0.f; u2a[tf][ct] = (f32x4)0.f; }

  short8v s3f[2][2], s4f[2][2], s1f[2][2];
#pragma unroll
  for (int tf = 0; tf < 2; ++tf)
#pragma unroll
    for (int ks = 0; ks < 2; ++ks) {
      size_t off = nbase + (tf*16 + ln)*64 + ks*32 + qw*8;
      s3f[tf][ks] = *(const short8v*)(S3 + off);
      s4f[tf][ks] = *(const short8v*)(S4 + off);
      s1f[tf][ks] = *(const short8v*)(S1 + off);
    }
#pragma unroll
  for (int ct = 0; ct < 4; ++ct)
#pragma unroll
    for (int ks = 0; ks < 2; ++ks) {
      short8v t2 = *(const short8v*)(lth + 1*4096 + ((ct*2 + ks)*64 + lane)*8);
      short8v t3 = *(const short8v*)(lth + 2*4096 + ((ct*2 + ks)*64 + lane)*8);
      short8v t1m = *(const short8v*)(lth + ((ct*2 + ks)*64 + lane)*8);
#pragma unroll
      for (int tf = 0; tf < 2; ++tf) {
        u5a[tf][ct] = MFMA16(s3f[tf][ks], t2, u5a[tf][ct], 0, 0, 0);
        u5a[tf][ct] = MFMA16(s4f[tf][ks], t3, u5a[tf][ct], 0, 0, 0);
        u2a[tf][ct] = MFMA16(s1f[tf][ks], t1m, u2a[tf][ct], 0, 0, 0);
      }
    }
#pragma unroll
  for (int tf = 0; tf < 2; ++tf)
#pragma unroll
    for (int ct = 0; ct < 4; ++ct) {
      int co = ct*16 + ln;
#pragma unroll
      for (int r = 0; r < 4; ++r) {
        int t = tf*16 + qw*4 + r;
        if (t >= T1) continue;
        float u2 = fmaxf(u2a[tf][ct][r], 0.f);
        float u5 = sigmoidf_(u5a[tf][ct][r]);
        float u6 = fmaxf(0.5f*(u2 + u5), 0.f);
        size_t off = nbase + t*64 + co;
        float x0 = bf2f(X00[off]);
        nu[off] = f2bf(fmaxf(0.9f*u6 + 0.1f*x0, 0.f));
      }
    }
}

// ---------- fused theta matmul + conv2 + gating -> d_out fp32 ----------
// block = one (node, b): 4 waves. Phase1: theta (wave ct=wv) -> LDS rows padded
// to 72 shorts (144B = 16B-aligned rows). Phase2: conv2 (wave ctq=wv).
__global__ __launch_bounds__(256) void k_thconv2(const short* __restrict__ u0,
                                                 const short* __restrict__ u1,
                                                 const short* __restrict__ thetapk,
                                                 const short* __restrict__ W2pk,
                                                 const float* __restrict__ b12,
                                                 const float* __restrict__ bc2,
                                                 float* __restrict__ out) {
  __shared__ short lds[34*72];
  int tid = threadIdx.x, lane = tid & 63, wv = tid >> 6;
  int ln = lane & 15, qw = lane >> 4;
  int bn = blockIdx.x;      // 0..399
  int b = blockIdx.y;
  const short* u; int i, Ipad;
  if (bn < NA) { u = u0; i = bn; Ipad = PA; }
  else         { u = u1; i = bn - NA; Ipad = PB; }
  // zero pad rows 30..33 (read by conv2 A-frags, discarded rows only feed t>=28)
  for (int z = tid; z < 4*72; z += 256) lds[30*72 + z] = 0;

  // phase 1: theta for this node, wave handles ct = wv
  f32x4 ac[2];
  ac[0] = (f32x4)0.f; ac[1] = (f32x4)0.f;
  size_t ubase = ((size_t)b*Ipad + i)*M1;
#pragma unroll
  for (int ks = 0; ks < 2; ++ks) {
    short8v bm = *(const short8v*)(thetapk + ((wv*2 + ks)*64 + lane)*8);
#pragma unroll
    for (int tf = 0; tf < 2; ++tf) {
      short8v af = *(const short8v*)(u + ubase + (tf*16 + ln)*64 + ks*32 + qw*8);
      ac[tf] = MFMA16(af, bm, ac[tf], 0, 0, 0);
    }
  }
#pragma unroll
  for (int tf = 0; tf < 2; ++tf)
#pragma unroll
    for (int r = 0; r < 4; ++r) {
      int t = tf*16 + qw*4 + r;
      if (t < T1) lds[t*72 + wv*16 + ln] = f2bf(fmaxf(ac[tf][r], 0.f));
    }
  __syncthreads();

  // phase 2: conv2, wave handles output quadrant ctq = wv (ct = wv, wv+4, wv+8)
  f32x4 a3[2][3];
#pragma unroll
  for (int tf = 0; tf < 2; ++tf)
#pragma unroll
    for (int s = 0; s < 3; ++s) a3[tf][s] = (f32x4)0.f;
  for (int ks = 0; ks < 6; ++ks) {
    short8v af[2];
#pragma unroll
    for (int tf = 0; tf < 2; ++tf) {
      int m = (tf*16 + ln)*64 + ks*32 + qw*8;
      af[tf] = *(const short8v*)(lds + (m >> 6)*72 + (m & 63));
    }
#pragma unroll
    for (int s = 0; s < 3; ++s) {
      int ct = wv + s*4;
      short8v bm = *(const short8v*)(W2pk + ((ct*6 + ks)*64 + lane)*8);
#pragma unroll
      for (int tf = 0; tf < 2; ++tf)
        a3[tf][s] = MFMA16(af[tf], bm, a3[tf][s], 0, 0, 0);
    }
  }
  int co = wv*16 + ln;
  float btm = b12[co], bp = bc2[co], bq = bc2[64 + co];
#pragma unroll
  for (int tf = 0; tf < 2; ++tf)
#pragma unroll
    for (int r = 0; r < 4; ++r) {
      int t = tf*16 + qw*4 + r;
      if (t >= T2) continue;
      float tm = a3[tf][0][r] + btm;
      float p  = a3[tf][1][r] + bp;
      float q  = a3[tf][2][r] + bq;
      out[((size_t)(b*400 + bn)*T2 + t)*64 + co] = (p + tm)*sigmoidf_(q);
    }
}

// ---------- batchnorm ----------
__global__ __launch_bounds__(256) void k_bn_stats(const float* __restrict__ y,
                                                  float* __restrict__ stats) {
  int n = blockIdx.x;
  int tid = threadIdx.x;
  float s = 0.f, ss = 0.f;
  for (int b = 0; b < BB; ++b) {
    const float* p = y + ((size_t)(b*400 + n))*(T2*64);
    for (int i2 = tid; i2 < T2*64; i2 += 256) {
      float v = p[i2];
      s += v; ss += v*v;
    }
  }
  __shared__ float rs[4], rss[4];
  for (int off = 32; off > 0; off >>= 1) {
    s += __shfl_down(s, off);
    ss += __shfl_down(ss, off);
  }
  if ((tid & 63) == 0) { rs[tid >> 6] = s; rss[tid >> 6] = ss; }
  __syncthreads();
  if (tid == 0) {
    float S = rs[0] + rs[1] + rs[2] + rs[3];
    float SS = rss[0] + rss[1] + rss[2] + rss[3];
    float mean = S/28672.f;
    float var = SS/28672.f - mean*mean;
    stats[n] = mean;
    stats[400 + n] = rsqrtf(var + 1e-5f);
  }
}

__global__ void k_bn_apply(float* __restrict__ y, const float* __restrict__ stats,
                           const float* __restrict__ gamma, const float* __restrict__ beta) {
  int idx = blockIdx.x*blockDim.x + threadIdx.x;
  const int total = BB*400*T2*64/4;
  for (; idx < total; idx += gridDim.x*blockDim.x) {
    int e = idx*4;
    int n = (e/(T2*64)) % 400;
    float mean = stats[n];
    float g = gamma[n]*stats[400 + n];
    float bt = beta[n];
    float4 v = ((float4*)y)[idx];
    v.x = (v.x - mean)*g + bt;
    v.y = (v.y - mean)*g + bt;
    v.z = (v.z - mean)*g + bt;
    v.w = (v.w - mean)*g + bt;
    ((float4*)y)[idx] = v;
  }
}

// ---------- host launcher ----------
extern "C" void kernel_launch(void* const* d_in, const int* in_sizes, int n_in,
                              void* d_out, int out_size, void* d_ws, size_t ws_size,
                              hipStream_t stream) {
  const float* X     = (const float*)d_in[0];
  const float* A00   = (const float*)d_in[1];
  const float* A01   = (const float*)d_in[2];
  const float* A10   = (const float*)d_in[3];
  const float* A11   = (const float*)d_in[4];
  const float* w11   = (const float*)d_in[5];
  const float* b11   = (const float*)d_in[6];
  const float* wc1   = (const float*)d_in[7];
  const float* bc1   = (const float*)d_in[8];
  const float* g1t1  = (const float*)d_in[9];
  const float* g1t2  = (const float*)d_in[10];
  const float* g1t3  = (const float*)d_in[11];
  const float* g2t1  = (const float*)d_in[12];
  const float* g2t2  = (const float*)d_in[13];
  const float* g2t3  = (const float*)d_in[14];
  const float* theta = (const float*)d_in[15];
  const float* w12   = (const float*)d_in[16];
  const float* b12   = (const float*)d_in[17];
  const float* wc2   = (const float*)d_in[18];
  const float* bc2   = (const float*)d_in[19];
  const float* gamma = (const float*)d_in[20];
  const float* beta  = (const float*)d_in[21];

  // ---- workspace layout (bf16/short units) ----
  short* ws = (short*)d_ws;
  size_t o = 0;
  short* t1a  = ws + o; o += (size_t)BB*PA*M1;
  short* t1b  = ws + o; o += (size_t)BB*PB*M1;
  short* u0   = ws + o; o += (size_t)BB*PA*M1;
  short* u1   = ws + o; o += (size_t)BB*PB*M1;
  short* uaT  = ws + o; o += (size_t)BB*M1*PA;
  short* ubT  = ws + o; o += (size_t)BB*M1*PB;
  short* slab = ws + o; o += 3*(size_t)BB*PB*M1 + 256;
  short* S1a = slab;
  short* S3a = slab + (size_t)BB*PA*M1;
  short* S4a = slab + 2*(size_t)BB*PA*M1;
  short* S1b = slab;
  short* S3b = slab + (size_t)BB*PB*M1;
  short* S4b = slab + 2*(size_t)BB*PB*M1;
  short* A00pk = ws + o; o += 12288;
  short* Mapk  = ws + o; o += 12288;
  short* A01pk = ws + o; o += 40960;
  short* A10pk = ws + o; o += 30720;
  short* A11pk = ws + o; o += 102400;
  short* Mbpk  = ws + o; o += 102400;
  short* thpk    = ws + o; o += 122880;
  short* thetapk = ws + o; o += 4096;
  short* W2pk    = ws + o; o += 36864;
  o = (o + 7) & ~(size_t)7;
  float* fws = (float*)(ws + o);
  float* Ma    = fws;
  float* Mb    = Ma + 6561;
  float* stats = Mb + 101761;
  float* W1t   = stats + 800;
  float* B1t   = W1t + 1152;

  // ---- prep ----
  k_prep_mm<<<424, 256, 0, stream>>>(A01, A10, Ma, Mb);
  k_pack_A<<<1176, 256, 0, stream>>>(A00, A01, A10, A11, Ma, Mb,
                                     A00pk, Mapk, A01pk, A10pk, A11pk, Mbpk);
  k_pack_th<<<646, 256, 0, stream>>>(g1t1, g1t2, g1t3, g2t1, g2t2, g2t3, theta,
                                     w12, wc2, w11, wc1, b11, bc1,
                                     thpk, thetapk, W2pk, W1t, B1t);
  k_tconv1<<<BB*400, 192, 0, stream>>>(X, W1t, B1t, t1a, t1b);
  k_transpose<<<dim3(PA/64, 4, BB), 256, 0, stream>>>(t1a, uaT, PA);
  k_transpose<<<dim3(PB/64, 4, BB), 256, 0, stream>>>(t1b, ubT, PB);

  for (int l = 0; l < 5; ++l) {
    // S4a = A01 @ u1T
    k_ngemm<1,4><<<dim3(15, 2, BB), 128, 0, stream>>>(ubT, PB, A01pk, nullptr, 8, 320,
                                                      S4a, nullptr, PA);
    // S1a = A00 @ u0T ; S3a = Ma @ u0T
    k_ngemm<2,2><<<dim3(15, 4, BB), 128, 0, stream>>>(uaT, PA, A00pk, Mapk, 8, 96,
                                                      S1a, S3a, PA);
    // epi a -> u0 (node-major)
    k_epi<<<dim3(21, BB), 256, 0, stream>>>(S1a, S3a, S4a, t1a,
                                            thpk + (size_t)(l*6)*4096, u0, NA, PA);
    // u0 -> uaT (m-major)
    k_transpose<<<dim3(PA/64, 4, BB), 256, 0, stream>>>(u0, uaT, PA);
    // S4b = A10 @ u0T
    k_ngemm<1,4><<<dim3(15, 5, BB), 128, 0, stream>>>(uaT, PA, A10pk, nullptr, 20, 96,
                                                      S4b, nullptr, PB);
    // S1b = A11 @ u1T ; S3b = Mb @ u1T
    k_ngemm<2,2><<<dim3(15, 10, BB), 128, 0, stream>>>(ubT, PB, A11pk, Mbpk, 20, 320,
                                                       S1b, S3b, PB);
    // epi b -> u1 (node-major)
    k_epi<<<dim3(80, BB), 256, 0, stream>>>(S1b, S3b, S4b, t1b,
                                            thpk + (size_t)(l*6 + 3)*4096, u1, NB, PB);
    if (l < 4)
      k_transpose<<<dim3(PB/64, 4, BB), 256, 0, stream>>>(u1, ubT, PB);
  }

  // fused theta + conv2 + gating -> d_out fp32
  k_thconv2<<<dim3(400, BB), 256, 0, stream>>>(u0, u1, thetapk, W2pk, b12, bc2,
                                               (float*)d_out);
  // batchnorm in place
  k_bn_stats<<<400, 256, 0, stream>>>((float*)d_out, stats);
  k_bn_apply<<<2048, 256, 0, stream>>>((float*)d_out, stats, gamma, beta);
}